// Round 11
// baseline (9836.329 us; speedup 1.0000x reference)
//
#include <hip/hip_runtime.h>
#include <hip/hip_bf16.h>
#include <cstdint>

#define HD 768
#define VOC 21128
#define VOCP 21248
#define NSTEPS 511
#define MROWS 4088      // 511*8
#define MPAD 4096
#define NBL 48          // lstm blocks (fan-in reduction; 48 << 256 CUs)
#define NTH 1024        // threads per lstm block

typedef float f32x4 __attribute__((ext_vector_type(4)));
typedef short short8 __attribute__((ext_vector_type(8)));

// ---- workspace layout (bytes) ----
// 0        : (unused)                                                (768)
// 768      : hw8[2][3072] u64  [tag16|fp16 h_even|fp16 h_odd|tag16]  (49152)
// 49920    : Hall[4088][768] f32                                     (12558336)
// 12632576 : WdT[768][768] f32                                       (2359296)
// 14991872 : T[4096][768] bf16                                       (6291456)
// 21283328 : WvB[21248][768] bf16                                    (32636928) -> end 53920256
#define OFF_HW   768
#define OFF_HALL 49920
#define OFF_WDT  12632576ULL
#define OFF_T    14991872ULL
#define OFF_WV   21283328ULL
#define PADH 772        // h_lds row stride (bank-conflict pad)

__device__ __forceinline__ unsigned short f2bf(float x) {
  unsigned u = __float_as_uint(x);
  u += 0x7FFFu + ((u >> 16) & 1u);   // RNE
  return (unsigned short)(u >> 16);
}

__device__ __forceinline__ void gl_lds16(const void* g, void* l) {
  __builtin_amdgcn_global_load_lds(
      (const __attribute__((address_space(1))) void*)g,
      (__attribute__((address_space(3))) void*)l, 16, 0, 0);
}

// relaxed agent-scope (sc1): coherent-point traffic, no cache-wide ops
__device__ __forceinline__ void st_u64(uint64_t* p, uint64_t v) {
  __hip_atomic_store(p, v, __ATOMIC_RELAXED, __HIP_MEMORY_SCOPE_AGENT);
}
__device__ __forceinline__ uint64_t ld_u64(const uint64_t* p) {
  return __hip_atomic_load(p, __ATOMIC_RELAXED, __HIP_MEMORY_SCOPE_AGENT);
}

// overflow-safe fast activations (rcp(inf)=0 gives exact saturation)
__device__ __forceinline__ float sigf(float x) {
  return __builtin_amdgcn_rcpf(1.f + __expf(-x));
}
__device__ __forceinline__ float tanhf_fast(float x) {
  float ax = fabsf(x);
  float e = __expf(-2.f * ax);                       // in (0,1], no overflow
  float t = (1.f - e) * __builtin_amdgcn_rcpf(1.f + e);
  return copysignf(t, x);
}

// ---------------- prep: WdT transpose, Wv->bf16 (padded), hw zero ---------
__global__ __launch_bounds__(256) void prep_kernel(
    const float* __restrict__ Wd, float* __restrict__ WdT,
    const float* __restrict__ Wv, unsigned short* __restrict__ WvB,
    uint64_t* __restrict__ hw8) {
  unsigned idx = blockIdx.x * 256 + threadIdx.x;
  unsigned stride = gridDim.x * 256;
  for (unsigned i = idx; i < 6144; i += stride) hw8[i] = 0;   // stale-tag kill
  for (unsigned i = idx; i < HD * HD; i += stride) {
    unsigned k = i / HD, j = i - k * HD;
    WdT[i] = Wd[j * HD + k];           // WdT[k][j] = Wd[j][k]
  }
  const unsigned NV = (unsigned)VOCP * HD, NVr = (unsigned)VOC * HD;
  for (unsigned i = idx; i < NV; i += stride)
    WvB[i] = f2bf(i < NVr ? Wv[i] : 0.f);
}

// -- lstm: persistent, 48 x 1024, self-validating 8B words, 3 polls/thread --
__global__ __launch_bounds__(NTH) void lstm_kernel(
    const float* __restrict__ cls, const float* __restrict__ Wih,
    const float* __restrict__ Whh, const float* __restrict__ bih,
    const float* __restrict__ bhh, uint64_t* __restrict__ hw8,
    float* __restrict__ Hall) {
  __shared__ float h_lds[8 * PADH];       // current h (or cls), [b][u] padded
  __shared__ float redf[16 * 64 * 9];     // [wave][row][b(pad 9)] partials
  __shared__ float sbias[64];             // combined gate biases, local rows
  const int t = threadIdx.x;
  const int blk = blockIdx.x;
  const int p_ = t & 31;               // row-pair 0..31 (64 rows/block)
  const int s_ = t >> 5;               // k-slice 0..31 (24 k each)
  const int ks = s_ * 24;
  const int r0 = 2 * p_, r1 = r0 + 1;  // local rows; gate=r>>4, unit=r&15
  const int grow0 = (r0 >> 4) * HD + blk * 16 + (r0 & 15);
  const int grow1 = (r1 >> 4) * HD + blk * 16 + (r1 & 15);
  float w0[24], w1[24];
#pragma unroll
  for (int j = 0; j < 24; ++j) {
    w0[j] = Wih[(size_t)grow0 * HD + ks + j];
    w1[j] = Wih[(size_t)grow1 * HD + ks + j];
  }
  if (t < 64) {
    int gr = (t >> 4) * HD + blk * 16 + (t & 15);
    sbias[t] = bih[gr] + bhh[gr];
  }
  float cstate = 0.f;
  const int wv = t >> 6;               // wave 0..15

  // one LSTM cell step; publishes packed [tag|h_even|h_odd|tag] u64 words
  auto do_step = [&](uint64_t* __restrict__ hw_out, int tag,
                     float* __restrict__ hall_row) {
    float acc0[8], acc1[8];
#pragma unroll
    for (int b = 0; b < 8; ++b) { acc0[b] = 0.f; acc1[b] = 0.f; }
#pragma unroll
    for (int b = 0; b < 8; ++b) {
      const float* hb = &h_lds[b * PADH + ks];
#pragma unroll
      for (int j4 = 0; j4 < 6; ++j4) {
        f32x4 hv = *reinterpret_cast<const f32x4*>(hb + j4 * 4);
#pragma unroll
        for (int e = 0; e < 4; ++e) {
          acc0[b] = fmaf(w0[j4 * 4 + e], hv[e], acc0[b]);
          acc1[b] = fmaf(w1[j4 * 4 + e], hv[e], acc1[b]);
        }
      }
    }
    // pair the wave's two k-slices (lane bit 5 == s_ bit 0)
#pragma unroll
    for (int b = 0; b < 8; ++b) {
      acc0[b] += __shfl_xor(acc0[b], 32);
      acc1[b] += __shfl_xor(acc1[b], 32);
    }
    if ((t & 63) < 32) {                // one half writes the wave partial
#pragma unroll
      for (int b = 0; b < 8; ++b) {
        redf[wv * 576 + r0 * 9 + b] = acc0[b];
        redf[wv * 576 + r1 * 9 + b] = acc1[b];
      }
    }
    __syncthreads();                     // redf complete
    if (t < 128) {
      int ul = t >> 3, b = t & 7;
      float gs[4];
#pragma unroll
      for (int g = 0; g < 4; ++g) {
        int r = g * 16 + ul;
        float s = sbias[r];
#pragma unroll
        for (int w2 = 0; w2 < 16; ++w2) s += redf[w2 * 576 + r * 9 + b];
        gs[g] = s;
      }
      float iv = sigf(gs[0]);
      float fv = sigf(gs[1]);
      float gv = tanhf_fast(gs[2]);
      float ov = sigf(gs[3]);
      cstate = fv * cstate + iv * gv;
      float hn = ov * tanhf_fast(cstate);
      // pair batches (b, b+1) in-wave; even-b lanes store one 8B atomic word
      float hp = __shfl_down(hn, 1);
      union { _Float16 f; unsigned short u; } c0, c1;
      c0.f = (_Float16)hn;
      c1.f = (_Float16)hp;
      if ((b & 1) == 0) {
        uint64_t wd = (uint64_t)(uint16_t)tag
                    | ((uint64_t)c0.u << 16)
                    | ((uint64_t)c1.u << 32)
                    | ((uint64_t)(uint16_t)tag << 48);
        st_u64(&hw_out[(blk * 16 + ul) * 4 + (b >> 1)], wd);
      }
      if (hall_row) hall_row[(size_t)b * HD + blk * 16 + ul] = hn;  // f32
    }
  };

  // pre-step: h1 = cell(cls, 0, 0) -> gates = cls@Wih^T + (bih+bhh)
  for (int i = t; i < 1536; i += NTH) {
    int b = i / 192, c4 = i - b * 192;
    *reinterpret_cast<f32x4*>(&h_lds[b * PADH + c4 * 4]) =
        reinterpret_cast<const f32x4*>(cls)[i];
  }
  __syncthreads();
  do_step(hw8 + 3072, 1, nullptr);       // h_1 -> parity 1, tag 1
  // switch to combined weights W_ih + W_hh (inside the scan, x == h)
#pragma unroll
  for (int j = 0; j < 24; ++j) {
    w0[j] += Whh[(size_t)grow0 * HD + ks + j];
    w1[j] += Whh[(size_t)grow1 * HD + ks + j];
  }
  for (int s = 1; s <= NSTEPS; ++s) {
    // poll own 3 u64 words of h_s (word g: unit=g>>2, batches 2(g&3),+1)
    // branch-free batched rounds: all 3 loads in flight, then validate.
    {
      const uint64_t* src = hw8 + (s & 1) * 3072;
      const uint32_t tg = (uint32_t)s;
      uint64_t w[3];
      bool ok;
      do {
        ok = true;
#pragma unroll
        for (int k = 0; k < 3; ++k) w[k] = ld_u64(&src[t + (k << 10)]);
#pragma unroll
        for (int k = 0; k < 3; ++k)
          ok &= ((uint32_t)(w[k] & 0xFFFFu) == tg) &
                ((uint32_t)(w[k] >> 48) == tg);
      } while (!ok);
#pragma unroll
      for (int k = 0; k < 3; ++k) {
        int g = t + (k << 10);
        int u = g >> 2, b0 = (g & 3) * 2;
        union { unsigned short u16; _Float16 f16; } d0, d1;
        d0.u16 = (unsigned short)((w[k] >> 16) & 0xFFFFu);
        d1.u16 = (unsigned short)((w[k] >> 32) & 0xFFFFu);
        h_lds[b0 * PADH + u] = (float)d0.f16;
        h_lds[(b0 + 1) * PADH + u] = (float)d1.f16;
      }
    }
    __syncthreads();                     // h_s staged in LDS
    do_step(hw8 + ((s + 1) & 1) * 3072, s + 1,
            Hall + (size_t)(s - 1) * (8 * HD));
  }
}

// ---------------- head: dense + gelu(erf) + LayerNorm -> T (bf16) ----------
__global__ __launch_bounds__(256) void head_kernel(
    const float* __restrict__ Hall, const float* __restrict__ WdT,
    const float* __restrict__ bd, const float* __restrict__ gamma,
    const float* __restrict__ beta, unsigned short* __restrict__ Tm) {
  __shared__ float hT[HD][16];
  __shared__ float rbuf[4][16];
  __shared__ float mu_s[16], rs_s[16];
  const int t = threadIdx.x;
  const int r0 = blockIdx.x * 16;
  {
    const int row = t & 15, ksl = t >> 4;
    const float* src = Hall + (size_t)(r0 + row) * HD + ksl * 48;
#pragma unroll
    for (int i = 0; i < 12; ++i) {
      f32x4 v = *reinterpret_cast<const f32x4*>(src + i * 4);
      int k = ksl * 48 + i * 4;
      hT[k][row] = v[0]; hT[k + 1][row] = v[1];
      hT[k + 2][row] = v[2]; hT[k + 3][row] = v[3];
    }
  }
  __syncthreads();
  float a0[16], a1[16], a2[16];
#pragma unroll
  for (int r = 0; r < 16; ++r) { a0[r] = 0.f; a1[r] = 0.f; a2[r] = 0.f; }
  for (int k = 0; k < HD; ++k) {
    float wa = WdT[(size_t)k * HD + t];
    float wb = WdT[(size_t)k * HD + t + 256];
    float wc = WdT[(size_t)k * HD + t + 512];
    f32x4 hv4[4];
#pragma unroll
    for (int q = 0; q < 4; ++q)
      hv4[q] = *reinterpret_cast<const f32x4*>(&hT[k][q * 4]);
#pragma unroll
    for (int r = 0; r < 16; ++r) {
      float hv = hv4[r >> 2][r & 3];
      a0[r] = fmaf(wa, hv, a0[r]);
      a1[r] = fmaf(wb, hv, a1[r]);
      a2[r] = fmaf(wc, hv, a2[r]);
    }
  }
  float g0 = gamma[t], g1 = gamma[t + 256], g2 = gamma[t + 512];
  float be0 = beta[t], be1 = beta[t + 256], be2 = beta[t + 512];
  float bd0 = bd[t], bd1 = bd[t + 256], bd2 = bd[t + 512];
#pragma unroll
  for (int r = 0; r < 16; ++r) {
    float x;
    x = a0[r] + bd0; a0[r] = 0.5f * x * (1.f + erff(x * 0.7071067811865476f));
    x = a1[r] + bd1; a1[r] = 0.5f * x * (1.f + erff(x * 0.7071067811865476f));
    x = a2[r] + bd2; a2[r] = 0.5f * x * (1.f + erff(x * 0.7071067811865476f));
  }
  float ps[16];
  const int lane = t & 63, wv = t >> 6;
#pragma unroll
  for (int r = 0; r < 16; ++r) ps[r] = a0[r] + a1[r] + a2[r];
#pragma unroll
  for (int r = 0; r < 16; ++r)
#pragma unroll
    for (int m = 1; m < 64; m <<= 1) ps[r] += __shfl_xor(ps[r], m);
  if (lane == 0) {
#pragma unroll
    for (int r = 0; r < 16; ++r) rbuf[wv][r] = ps[r];
  }
  __syncthreads();
  if (t < 16) mu_s[t] = (rbuf[0][t] + rbuf[1][t] + rbuf[2][t] + rbuf[3][t]) * (1.f / HD);
  __syncthreads();
#pragma unroll
  for (int r = 0; r < 16; ++r) {
    float mu = mu_s[r];
    float d0 = a0[r] - mu, d1 = a1[r] - mu, d2 = a2[r] - mu;
    ps[r] = d0 * d0 + d1 * d1 + d2 * d2;
  }
#pragma unroll
  for (int r = 0; r < 16; ++r)
#pragma unroll
    for (int m = 1; m < 64; m <<= 1) ps[r] += __shfl_xor(ps[r], m);
  if (lane == 0) {
#pragma unroll
    for (int r = 0; r < 16; ++r) rbuf[wv][r] = ps[r];
  }
  __syncthreads();
  if (t < 16)
    rs_s[t] = 1.f / sqrtf((rbuf[0][t] + rbuf[1][t] + rbuf[2][t] + rbuf[3][t]) * (1.f / HD) + 1e-12f);
  __syncthreads();
#pragma unroll
  for (int r = 0; r < 16; ++r) {
    float mu = mu_s[r], rs = rs_s[r];
    size_t ro = (size_t)(r0 + r) * HD;
    Tm[ro + t]       = f2bf((a0[r] - mu) * rs * g0 + be0);
    Tm[ro + t + 256] = f2bf((a1[r] - mu) * rs * g1 + be1);
    Tm[ro + t + 512] = f2bf((a2[r] - mu) * rs * g2 + be2);
  }
}

// ---------------- decoder GEMM: out = T @ WvB^T + bvoc  (bf16 MFMA) -------
__global__ __launch_bounds__(256) void gemm_kernel(
    const unsigned short* __restrict__ Tm, const unsigned short* __restrict__ Wv,
    const float* __restrict__ bvoc, float* __restrict__ out) {
  __shared__ unsigned short As[128 * 64];
  __shared__ unsigned short Bs[128 * 64];
  const int t = threadIdx.x;
  const int lane = t & 63, wid = t >> 6;
  const int wm = wid >> 1, wn = wid & 1;
  const int m0 = blockIdx.y * 128, n0 = blockIdx.x * 128;
  const int lrow = lane & 15, lgrp = lane >> 4;
  f32x4 acc[4][4] = {};
  for (int kt = 0; kt < HD; kt += 64) {
#pragma unroll
    for (int it = 0; it < 4; ++it) {
      int slot = it * 256 + t;
      int row = slot >> 3, g = slot & 7;
      int sg = g ^ (row & 7);                       // pre-swizzled source
      const unsigned short* sa = Tm + (size_t)(m0 + row) * HD + kt + sg * 8;
      const unsigned short* sb = Wv + (size_t)(n0 + row) * HD + kt + sg * 8;
      unsigned short* da = &As[(it * 256 + wid * 64) * 8];  // wave-uniform base
      unsigned short* db = &Bs[(it * 256 + wid * 64) * 8];
      gl_lds16(sa, da);
      gl_lds16(sb, db);
    }
    __syncthreads();
#pragma unroll
    for (int kk = 0; kk < 2; ++kk) {
      short8 af[4], bfr[4];
#pragma unroll
      for (int i = 0; i < 4; ++i) {
        int row = wm * 64 + i * 16 + lrow;
        int gg = (kk * 4 + lgrp) ^ (row & 7);       // swizzled read
        af[i] = *reinterpret_cast<const short8*>(&As[row * 64 + gg * 8]);
      }
#pragma unroll
      for (int j = 0; j < 4; ++j) {
        int row = wn * 64 + j * 16 + lrow;
        int gg = (kk * 4 + lgrp) ^ (row & 7);
        bfr[j] = *reinterpret_cast<const short8*>(&Bs[row * 64 + gg * 8]);
      }
#pragma unroll
      for (int i = 0; i < 4; ++i)
#pragma unroll
        for (int j = 0; j < 4; ++j)
          acc[i][j] = __builtin_amdgcn_mfma_f32_16x16x32_bf16(af[i], bfr[j], acc[i][j], 0, 0, 0);
    }
    __syncthreads();
  }
#pragma unroll
  for (int j = 0; j < 4; ++j) {
    int col = n0 + wn * 64 + j * 16 + lrow;
    bool cok = col < VOC;
    float bv = cok ? bvoc[col] : 0.f;
#pragma unroll
    for (int i = 0; i < 4; ++i) {
      int rbase = m0 + wm * 64 + i * 16 + lgrp * 4;
#pragma unroll
      for (int e = 0; e < 4; ++e) {
        int row = rbase + e;
        if (cok && row < MROWS) out[(size_t)row * VOC + col] = acc[i][j][e] + bv;
      }
    }
  }
}

extern "C" void kernel_launch(void* const* d_in, const int* in_sizes, int n_in,
                              void* d_out, int out_size, void* d_ws, size_t ws_size,
                              hipStream_t stream) {
  (void)in_sizes; (void)n_in; (void)out_size; (void)ws_size;
  const float* cls  = (const float*)d_in[0];
  const float* Wih  = (const float*)d_in[1];
  const float* Whh  = (const float*)d_in[2];
  const float* bih  = (const float*)d_in[3];
  const float* bhh  = (const float*)d_in[4];
  const float* Wd   = (const float*)d_in[5];
  const float* bd   = (const float*)d_in[6];
  const float* gmm  = (const float*)d_in[7];
  const float* bet  = (const float*)d_in[8];
  const float* Wv   = (const float*)d_in[9];
  const float* bvoc = (const float*)d_in[10];
  char* ws = (char*)d_ws;
  uint64_t* hw8 = (uint64_t*)(ws + OFF_HW);
  float* Hall  = (float*)(ws + OFF_HALL);
  float* WdT   = (float*)(ws + OFF_WDT);
  unsigned short* Tm  = (unsigned short*)(ws + OFF_T);
  unsigned short* WvB = (unsigned short*)(ws + OFF_WV);
  float* out = (float*)d_out;

  hipLaunchKernelGGL(prep_kernel, dim3(4096), dim3(256), 0, stream, Wd, WdT, Wv, WvB, hw8);
  hipLaunchKernelGGL(lstm_kernel, dim3(NBL), dim3(NTH), 0, stream,
                     cls, Wih, Whh, bih, bhh, hw8, Hall);
  hipLaunchKernelGGL(head_kernel, dim3(MPAD / 16), dim3(256), 0, stream,
                     Hall, WdT, bd, gmm, bet, Tm);
  hipLaunchKernelGGL(gemm_kernel, dim3(VOCP / 128, MPAD / 128), dim3(256), 0, stream,
                     Tm, WvB, bvoc, out);
}

// Round 12
// 2445.633 us; speedup vs baseline: 4.0220x; 4.0220x over previous
//
#include <hip/hip_runtime.h>
#include <hip/hip_bf16.h>
#include <cstdint>

#define HD 768
#define VOC 21128
#define VOCP 21248
#define NSTEPS 511
#define MROWS 4088      // 511*8
#define MPAD 4096
#define NBL 96          // lstm blocks (fan-in test; 96 << 256 CUs)
#define NTH 512         // threads per lstm block (8 waves -> VGPR budget 256)

typedef float f32x4 __attribute__((ext_vector_type(4)));
typedef short short8 __attribute__((ext_vector_type(8)));

// ---- workspace layout (bytes) ----
// 0        : (unused)                                                (768)
// 768      : hw8[2][3072] u64  [tag16|fp16 h_even|fp16 h_odd|tag16]  (49152)
// 49920    : Hall[4088][768] f32                                     (12558336)
// 12632576 : WdT[768][768] f32                                       (2359296)
// 14991872 : T[4096][768] bf16                                       (6291456)
// 21283328 : WvB[21248][768] bf16                                    (32636928) -> end 53920256
#define OFF_HW   768
#define OFF_HALL 49920
#define OFF_WDT  12632576ULL
#define OFF_T    14991872ULL
#define OFF_WV   21283328ULL
#define PADH 772        // h_lds row stride (bank-conflict pad)

__device__ __forceinline__ unsigned short f2bf(float x) {
  unsigned u = __float_as_uint(x);
  u += 0x7FFFu + ((u >> 16) & 1u);   // RNE
  return (unsigned short)(u >> 16);
}

__device__ __forceinline__ void gl_lds16(const void* g, void* l) {
  __builtin_amdgcn_global_load_lds(
      (const __attribute__((address_space(1))) void*)g,
      (__attribute__((address_space(3))) void*)l, 16, 0, 0);
}

// relaxed agent-scope (sc1): coherent-point traffic, no cache-wide ops
__device__ __forceinline__ void st_u64(uint64_t* p, uint64_t v) {
  __hip_atomic_store(p, v, __ATOMIC_RELAXED, __HIP_MEMORY_SCOPE_AGENT);
}
__device__ __forceinline__ uint64_t ld_u64(const uint64_t* p) {
  return __hip_atomic_load(p, __ATOMIC_RELAXED, __HIP_MEMORY_SCOPE_AGENT);
}

// overflow-safe fast activations (rcp(inf)=0 gives exact saturation)
__device__ __forceinline__ float sigf(float x) {
  return __builtin_amdgcn_rcpf(1.f + __expf(-x));
}
__device__ __forceinline__ float tanhf_fast(float x) {
  float ax = fabsf(x);
  float e = __expf(-2.f * ax);                       // in (0,1], no overflow
  float t = (1.f - e) * __builtin_amdgcn_rcpf(1.f + e);
  return copysignf(t, x);
}

// ---------------- prep: WdT transpose, Wv->bf16 (padded), hw zero ---------
__global__ __launch_bounds__(256) void prep_kernel(
    const float* __restrict__ Wd, float* __restrict__ WdT,
    const float* __restrict__ Wv, unsigned short* __restrict__ WvB,
    uint64_t* __restrict__ hw8) {
  unsigned idx = blockIdx.x * 256 + threadIdx.x;
  unsigned stride = gridDim.x * 256;
  for (unsigned i = idx; i < 6144; i += stride) hw8[i] = 0;   // stale-tag kill
  for (unsigned i = idx; i < HD * HD; i += stride) {
    unsigned k = i / HD, j = i - k * HD;
    WdT[i] = Wd[j * HD + k];           // WdT[k][j] = Wd[j][k]
  }
  const unsigned NV = (unsigned)VOCP * HD, NVr = (unsigned)VOC * HD;
  for (unsigned i = idx; i < NV; i += stride)
    WvB[i] = f2bf(i < NVr ? Wv[i] : 0.f);
}

// -- lstm: persistent, 96 x 512, self-validating 8B words, 6 polls/thread --
__global__ __launch_bounds__(NTH) void lstm_kernel(
    const float* __restrict__ cls, const float* __restrict__ Wih,
    const float* __restrict__ Whh, const float* __restrict__ bih,
    const float* __restrict__ bhh, uint64_t* __restrict__ hw8,
    float* __restrict__ Hall) {
  __shared__ float h_lds[8 * PADH];       // current h (or cls), [b][u] padded
  __shared__ float redf[8 * 32 * 9];      // [wave][row][b(pad 9)] partials
  __shared__ float sbias[32];             // combined gate biases, local rows
  const int t = threadIdx.x;
  const int blk = blockIdx.x;
  const int p_ = t & 15;               // row-pair 0..15 (32 rows/block)
  const int s_ = t >> 4;               // k-slice 0..31 (24 k each)
  const int ks = s_ * 24;
  const int r0 = 2 * p_, r1 = r0 + 1;  // local rows; gate=r>>3, unit=r&7
  const int grow0 = (r0 >> 3) * HD + blk * 8 + (r0 & 7);
  const int grow1 = (r1 >> 3) * HD + blk * 8 + (r1 & 7);
  float w0[24], w1[24];
#pragma unroll
  for (int j = 0; j < 24; ++j) {
    w0[j] = Wih[(size_t)grow0 * HD + ks + j];
    w1[j] = Wih[(size_t)grow1 * HD + ks + j];
  }
  if (t < 32) {
    int gr = (t >> 3) * HD + blk * 8 + (t & 7);
    sbias[t] = bih[gr] + bhh[gr];
  }
  float cstate = 0.f;
  const int wv = t >> 6;               // wave 0..7

  // one LSTM cell step; publishes packed [tag|h_even|h_odd|tag] u64 words
  auto do_step = [&](uint64_t* __restrict__ hw_out, int tag,
                     float* __restrict__ hall_row) {
    float acc0[8], acc1[8];
#pragma unroll
    for (int b = 0; b < 8; ++b) { acc0[b] = 0.f; acc1[b] = 0.f; }
#pragma unroll
    for (int b = 0; b < 8; ++b) {
      const float* hb = &h_lds[b * PADH + ks];
#pragma unroll
      for (int j4 = 0; j4 < 6; ++j4) {
        f32x4 hv = *reinterpret_cast<const f32x4*>(hb + j4 * 4);
#pragma unroll
        for (int e = 0; e < 4; ++e) {
          acc0[b] = fmaf(w0[j4 * 4 + e], hv[e], acc0[b]);
          acc1[b] = fmaf(w1[j4 * 4 + e], hv[e], acc1[b]);
        }
      }
    }
    // reduce the wave's 4 k-slices (lane bits 4,5 = s_ low bits)
#pragma unroll
    for (int b = 0; b < 8; ++b) {
      acc0[b] += __shfl_xor(acc0[b], 16);
      acc0[b] += __shfl_xor(acc0[b], 32);
      acc1[b] += __shfl_xor(acc1[b], 16);
      acc1[b] += __shfl_xor(acc1[b], 32);
    }
    if ((t & 63) < 16) {                // one lane per row-pair per wave
#pragma unroll
      for (int b = 0; b < 8; ++b) {
        redf[wv * 288 + r0 * 9 + b] = acc0[b];
        redf[wv * 288 + r1 * 9 + b] = acc1[b];
      }
    }
    __syncthreads();                     // redf complete
    if (t < 64) {
      int ul = t >> 3, b = t & 7;        // unit 0..7, batch 0..7
      float gs[4];
#pragma unroll
      for (int g = 0; g < 4; ++g) {
        int r = g * 8 + ul;
        float s = sbias[r];
#pragma unroll
        for (int w2 = 0; w2 < 8; ++w2) s += redf[w2 * 288 + r * 9 + b];
        gs[g] = s;
      }
      float iv = sigf(gs[0]);
      float fv = sigf(gs[1]);
      float gv = tanhf_fast(gs[2]);
      float ov = sigf(gs[3]);
      cstate = fv * cstate + iv * gv;
      float hn = ov * tanhf_fast(cstate);
      // pair batches (b, b+1) in-wave; even-b lanes store one 8B atomic word
      float hp = __shfl_down(hn, 1);
      union { _Float16 f; unsigned short u; } c0, c1;
      c0.f = (_Float16)hn;
      c1.f = (_Float16)hp;
      if ((b & 1) == 0) {
        uint64_t wd = (uint64_t)(uint16_t)tag
                    | ((uint64_t)c0.u << 16)
                    | ((uint64_t)c1.u << 32)
                    | ((uint64_t)(uint16_t)tag << 48);
        st_u64(&hw_out[(blk * 8 + ul) * 4 + (b >> 1)], wd);
      }
      if (hall_row) hall_row[(size_t)b * HD + blk * 8 + ul] = hn;  // f32
    }
  };

  // pre-step: h1 = cell(cls, 0, 0) -> gates = cls@Wih^T + (bih+bhh)
  for (int i = t; i < 1536; i += NTH) {
    int b = i / 192, c4 = i - b * 192;
    *reinterpret_cast<f32x4*>(&h_lds[b * PADH + c4 * 4]) =
        reinterpret_cast<const f32x4*>(cls)[i];
  }
  __syncthreads();
  do_step(hw8 + 3072, 1, nullptr);       // h_1 -> parity 1, tag 1
  // switch to combined weights W_ih + W_hh (inside the scan, x == h)
#pragma unroll
  for (int j = 0; j < 24; ++j) {
    w0[j] += Whh[(size_t)grow0 * HD + ks + j];
    w1[j] += Whh[(size_t)grow1 * HD + ks + j];
  }
  for (int s = 1; s <= NSTEPS; ++s) {
    // poll own 6 u64 words of h_s (word g: unit=g>>2, batches 2(g&3),+1)
    // branch-free batched rounds: all 6 loads in flight, then validate.
    {
      const uint64_t* src = hw8 + (s & 1) * 3072;
      const uint32_t tg = (uint32_t)s;
      uint64_t w[6];
      bool ok;
      do {
        ok = true;
#pragma unroll
        for (int k = 0; k < 6; ++k) w[k] = ld_u64(&src[t + (k << 9)]);
#pragma unroll
        for (int k = 0; k < 6; ++k)
          ok &= ((uint32_t)(w[k] & 0xFFFFu) == tg) &
                ((uint32_t)(w[k] >> 48) == tg);
      } while (!ok);
#pragma unroll
      for (int k = 0; k < 6; ++k) {
        int g = t + (k << 9);
        int u = g >> 2, b0 = (g & 3) * 2;
        union { unsigned short u16; _Float16 f16; } d0, d1;
        d0.u16 = (unsigned short)((w[k] >> 16) & 0xFFFFu);
        d1.u16 = (unsigned short)((w[k] >> 32) & 0xFFFFu);
        h_lds[b0 * PADH + u] = (float)d0.f16;
        h_lds[(b0 + 1) * PADH + u] = (float)d1.f16;
      }
    }
    __syncthreads();                     // h_s staged in LDS
    do_step(hw8 + ((s + 1) & 1) * 3072, s + 1,
            Hall + (size_t)(s - 1) * (8 * HD));
  }
}

// ---------------- head: dense + gelu(erf) + LayerNorm -> T (bf16) ----------
__global__ __launch_bounds__(256) void head_kernel(
    const float* __restrict__ Hall, const float* __restrict__ WdT,
    const float* __restrict__ bd, const float* __restrict__ gamma,
    const float* __restrict__ beta, unsigned short* __restrict__ Tm) {
  __shared__ float hT[HD][16];
  __shared__ float rbuf[4][16];
  __shared__ float mu_s[16], rs_s[16];
  const int t = threadIdx.x;
  const int r0 = blockIdx.x * 16;
  {
    const int row = t & 15, ksl = t >> 4;
    const float* src = Hall + (size_t)(r0 + row) * HD + ksl * 48;
#pragma unroll
    for (int i = 0; i < 12; ++i) {
      f32x4 v = *reinterpret_cast<const f32x4*>(src + i * 4);
      int k = ksl * 48 + i * 4;
      hT[k][row] = v[0]; hT[k + 1][row] = v[1];
      hT[k + 2][row] = v[2]; hT[k + 3][row] = v[3];
    }
  }
  __syncthreads();
  float a0[16], a1[16], a2[16];
#pragma unroll
  for (int r = 0; r < 16; ++r) { a0[r] = 0.f; a1[r] = 0.f; a2[r] = 0.f; }
  for (int k = 0; k < HD; ++k) {
    float wa = WdT[(size_t)k * HD + t];
    float wb = WdT[(size_t)k * HD + t + 256];
    float wc = WdT[(size_t)k * HD + t + 512];
    f32x4 hv4[4];
#pragma unroll
    for (int q = 0; q < 4; ++q)
      hv4[q] = *reinterpret_cast<const f32x4*>(&hT[k][q * 4]);
#pragma unroll
    for (int r = 0; r < 16; ++r) {
      float hv = hv4[r >> 2][r & 3];
      a0[r] = fmaf(wa, hv, a0[r]);
      a1[r] = fmaf(wb, hv, a1[r]);
      a2[r] = fmaf(wc, hv, a2[r]);
    }
  }
  float g0 = gamma[t], g1 = gamma[t + 256], g2 = gamma[t + 512];
  float be0 = beta[t], be1 = beta[t + 256], be2 = beta[t + 512];
  float bd0 = bd[t], bd1 = bd[t + 256], bd2 = bd[t + 512];
#pragma unroll
  for (int r = 0; r < 16; ++r) {
    float x;
    x = a0[r] + bd0; a0[r] = 0.5f * x * (1.f + erff(x * 0.7071067811865476f));
    x = a1[r] + bd1; a1[r] = 0.5f * x * (1.f + erff(x * 0.7071067811865476f));
    x = a2[r] + bd2; a2[r] = 0.5f * x * (1.f + erff(x * 0.7071067811865476f));
  }
  float ps[16];
  const int lane = t & 63, wv = t >> 6;
#pragma unroll
  for (int r = 0; r < 16; ++r) ps[r] = a0[r] + a1[r] + a2[r];
#pragma unroll
  for (int r = 0; r < 16; ++r)
#pragma unroll
    for (int m = 1; m < 64; m <<= 1) ps[r] += __shfl_xor(ps[r], m);
  if (lane == 0) {
#pragma unroll
    for (int r = 0; r < 16; ++r) rbuf[wv][r] = ps[r];
  }
  __syncthreads();
  if (t < 16) mu_s[t] = (rbuf[0][t] + rbuf[1][t] + rbuf[2][t] + rbuf[3][t]) * (1.f / HD);
  __syncthreads();
#pragma unroll
  for (int r = 0; r < 16; ++r) {
    float mu = mu_s[r];
    float d0 = a0[r] - mu, d1 = a1[r] - mu, d2 = a2[r] - mu;
    ps[r] = d0 * d0 + d1 * d1 + d2 * d2;
  }
#pragma unroll
  for (int r = 0; r < 16; ++r)
#pragma unroll
    for (int m = 1; m < 64; m <<= 1) ps[r] += __shfl_xor(ps[r], m);
  if (lane == 0) {
#pragma unroll
    for (int r = 0; r < 16; ++r) rbuf[wv][r] = ps[r];
  }
  __syncthreads();
  if (t < 16)
    rs_s[t] = 1.f / sqrtf((rbuf[0][t] + rbuf[1][t] + rbuf[2][t] + rbuf[3][t]) * (1.f / HD) + 1e-12f);
  __syncthreads();
#pragma unroll
  for (int r = 0; r < 16; ++r) {
    float mu = mu_s[r], rs = rs_s[r];
    size_t ro = (size_t)(r0 + r) * HD;
    Tm[ro + t]       = f2bf((a0[r] - mu) * rs * g0 + be0);
    Tm[ro + t + 256] = f2bf((a1[r] - mu) * rs * g1 + be1);
    Tm[ro + t + 512] = f2bf((a2[r] - mu) * rs * g2 + be2);
  }
}

// ---------------- decoder GEMM: out = T @ WvB^T + bvoc  (bf16 MFMA) -------
__global__ __launch_bounds__(256) void gemm_kernel(
    const unsigned short* __restrict__ Tm, const unsigned short* __restrict__ Wv,
    const float* __restrict__ bvoc, float* __restrict__ out) {
  __shared__ unsigned short As[128 * 64];
  __shared__ unsigned short Bs[128 * 64];
  const int t = threadIdx.x;
  const int lane = t & 63, wid = t >> 6;
  const int wm = wid >> 1, wn = wid & 1;
  const int m0 = blockIdx.y * 128, n0 = blockIdx.x * 128;
  const int lrow = lane & 15, lgrp = lane >> 4;
  f32x4 acc[4][4] = {};
  for (int kt = 0; kt < HD; kt += 64) {
#pragma unroll
    for (int it = 0; it < 4; ++it) {
      int slot = it * 256 + t;
      int row = slot >> 3, g = slot & 7;
      int sg = g ^ (row & 7);                       // pre-swizzled source
      const unsigned short* sa = Tm + (size_t)(m0 + row) * HD + kt + sg * 8;
      const unsigned short* sb = Wv + (size_t)(n0 + row) * HD + kt + sg * 8;
      unsigned short* da = &As[(it * 256 + wid * 64) * 8];  // wave-uniform base
      unsigned short* db = &Bs[(it * 256 + wid * 64) * 8];
      gl_lds16(sa, da);
      gl_lds16(sb, db);
    }
    __syncthreads();
#pragma unroll
    for (int kk = 0; kk < 2; ++kk) {
      short8 af[4], bfr[4];
#pragma unroll
      for (int i = 0; i < 4; ++i) {
        int row = wm * 64 + i * 16 + lrow;
        int gg = (kk * 4 + lgrp) ^ (row & 7);       // swizzled read
        af[i] = *reinterpret_cast<const short8*>(&As[row * 64 + gg * 8]);
      }
#pragma unroll
      for (int j = 0; j < 4; ++j) {
        int row = wn * 64 + j * 16 + lrow;
        int gg = (kk * 4 + lgrp) ^ (row & 7);
        bfr[j] = *reinterpret_cast<const short8*>(&Bs[row * 64 + gg * 8]);
      }
#pragma unroll
      for (int i = 0; i < 4; ++i)
#pragma unroll
        for (int j = 0; j < 4; ++j)
          acc[i][j] = __builtin_amdgcn_mfma_f32_16x16x32_bf16(af[i], bfr[j], acc[i][j], 0, 0, 0);
    }
    __syncthreads();
  }
#pragma unroll
  for (int j = 0; j < 4; ++j) {
    int col = n0 + wn * 64 + j * 16 + lrow;
    bool cok = col < VOC;
    float bv = cok ? bvoc[col] : 0.f;
#pragma unroll
    for (int i = 0; i < 4; ++i) {
      int rbase = m0 + wm * 64 + i * 16 + lgrp * 4;
#pragma unroll
      for (int e = 0; e < 4; ++e) {
        int row = rbase + e;
        if (cok && row < MROWS) out[(size_t)row * VOC + col] = acc[i][j][e] + bv;
      }
    }
  }
}

extern "C" void kernel_launch(void* const* d_in, const int* in_sizes, int n_in,
                              void* d_out, int out_size, void* d_ws, size_t ws_size,
                              hipStream_t stream) {
  (void)in_sizes; (void)n_in; (void)out_size; (void)ws_size;
  const float* cls  = (const float*)d_in[0];
  const float* Wih  = (const float*)d_in[1];
  const float* Whh  = (const float*)d_in[2];
  const float* bih  = (const float*)d_in[3];
  const float* bhh  = (const float*)d_in[4];
  const float* Wd   = (const float*)d_in[5];
  const float* bd   = (const float*)d_in[6];
  const float* gmm  = (const float*)d_in[7];
  const float* bet  = (const float*)d_in[8];
  const float* Wv   = (const float*)d_in[9];
  const float* bvoc = (const float*)d_in[10];
  char* ws = (char*)d_ws;
  uint64_t* hw8 = (uint64_t*)(ws + OFF_HW);
  float* Hall  = (float*)(ws + OFF_HALL);
  float* WdT   = (float*)(ws + OFF_WDT);
  unsigned short* Tm  = (unsigned short*)(ws + OFF_T);
  unsigned short* WvB = (unsigned short*)(ws + OFF_WV);
  float* out = (float*)d_out;

  hipLaunchKernelGGL(prep_kernel, dim3(4096), dim3(256), 0, stream, Wd, WdT, Wv, WvB, hw8);
  hipLaunchKernelGGL(lstm_kernel, dim3(NBL), dim3(NTH), 0, stream,
                     cls, Wih, Whh, bih, bhh, hw8, Hall);
  hipLaunchKernelGGL(head_kernel, dim3(MPAD / 16), dim3(256), 0, stream,
                     Hall, WdT, bd, gmm, bet, Tm);
  hipLaunchKernelGGL(gemm_kernel, dim3(VOCP / 128, MPAD / 128), dim3(256), 0, stream,
                     Tm, WvB, bvoc, out);
}

// Round 13
// 2157.735 us; speedup vs baseline: 4.5586x; 1.1334x over previous
//
#include <hip/hip_runtime.h>
#include <hip/hip_bf16.h>
#include <cstdint>

#define HD 768
#define VOC 21128
#define VOCP 21248
#define NSTEPS 511
#define MROWS 4088      // 511*8
#define MPAD 4096
#define NBL 192         // lstm blocks (co-resident, 192 < 256 CUs)

typedef float f32x4 __attribute__((ext_vector_type(4)));
typedef short short8 __attribute__((ext_vector_type(8)));

// ---- workspace layout (bytes) ----
// 0        : (unused)                                                (768)
// 768      : hw[2][6144] u32  packed h words [tag16|fp16], [u][b]    (49152)
// 49920    : Hall[4088][768] f32                                     (12558336)
// 12632576 : WdT[768][768] f32                                       (2359296)
// 14991872 : T[4096][768] bf16                                       (6291456)
// 21283328 : WvB[21248][768] bf16                                    (32636928) -> end 53920256
#define OFF_HW   768
#define OFF_HALL 49920
#define OFF_WDT  12632576ULL
#define OFF_T    14991872ULL
#define OFF_WV   21283328ULL
#define PADH 772        // h_lds row stride (bank-conflict pad)

__device__ __forceinline__ unsigned short f2bf(float x) {
  unsigned u = __float_as_uint(x);
  u += 0x7FFFu + ((u >> 16) & 1u);   // RNE
  return (unsigned short)(u >> 16);
}

__device__ __forceinline__ void gl_lds16(const void* g, void* l) {
  __builtin_amdgcn_global_load_lds(
      (const __attribute__((address_space(1))) void*)g,
      (__attribute__((address_space(3))) void*)l, 16, 0, 0);
}

// relaxed agent-scope (sc1): coherent-point traffic, no cache-wide ops
__device__ __forceinline__ void st_u32(uint32_t* p, uint32_t v) {
  __hip_atomic_store(p, v, __ATOMIC_RELAXED, __HIP_MEMORY_SCOPE_AGENT);
}
__device__ __forceinline__ uint32_t ld_u32(const uint32_t* p) {
  return __hip_atomic_load(p, __ATOMIC_RELAXED, __HIP_MEMORY_SCOPE_AGENT);
}

// wave-local xor-swizzles (within 32-lane halves; BitMode patterns)
__device__ __forceinline__ float swz8(float x) {
  return __int_as_float(__builtin_amdgcn_ds_swizzle(__float_as_int(x), 0x201F));
}
__device__ __forceinline__ float swz16(float x) {
  return __int_as_float(__builtin_amdgcn_ds_swizzle(__float_as_int(x), 0x401F));
}

// overflow-safe fast activations (rcp(inf)=0 gives exact saturation)
__device__ __forceinline__ float sigf(float x) {
  return __builtin_amdgcn_rcpf(1.f + __expf(-x));
}
__device__ __forceinline__ float tanhf_fast(float x) {
  float ax = fabsf(x);
  float e = __expf(-2.f * ax);                       // in (0,1], no overflow
  float t = (1.f - e) * __builtin_amdgcn_rcpf(1.f + e);
  return copysignf(t, x);
}

// ---------------- prep: WdT transpose, Wv->bf16 (padded), hw zero ---------
__global__ __launch_bounds__(256) void prep_kernel(
    const float* __restrict__ Wd, float* __restrict__ WdT,
    const float* __restrict__ Wv, unsigned short* __restrict__ WvB,
    uint32_t* __restrict__ hw) {
  unsigned idx = blockIdx.x * 256 + threadIdx.x;
  unsigned stride = gridDim.x * 256;
  for (unsigned i = idx; i < 12288; i += stride) hw[i] = 0;   // stale-tag kill
  for (unsigned i = idx; i < HD * HD; i += stride) {
    unsigned k = i / HD, j = i - k * HD;
    WdT[i] = Wd[j * HD + k];           // WdT[k][j] = Wd[j][k]
  }
  const unsigned NV = (unsigned)VOCP * HD, NVr = (unsigned)VOC * HD;
  for (unsigned i = idx; i < NV; i += stride)
    WvB[i] = f2bf(i < NVr ? Wv[i] : 0.f);
}

// ------ lstm: persistent, 192 blocks, self-validating word protocol -------
// (round-7 configuration: global best, 1734 us measured)
__global__ __launch_bounds__(256) void lstm_kernel(
    const float* __restrict__ cls, const float* __restrict__ Wih,
    const float* __restrict__ Whh, const float* __restrict__ bih,
    const float* __restrict__ bhh, uint32_t* __restrict__ hw,
    float* __restrict__ Hall) {
  __shared__ float h_lds[8 * PADH];       // current h (or cls), [b][u] padded
  __shared__ float red[4][2][16][8];      // [wave][half][row][b] partials
  __shared__ float sbias[16];             // combined gate biases, local rows
  const int t = threadIdx.x;
  const int blk = blockIdx.x;
  const int p_ = t & 7;                // row-pair 0..7 (16 rows/block)
  const int s_ = t >> 3;               // k-slice 0..31 (24 k each)
  const int ks = s_ * 24;
  const int r0 = 2 * p_, r1 = r0 + 1;  // local rows; gate=r>>2, unit=r&3
  const int grow0 = (r0 >> 2) * HD + blk * 4 + (r0 & 3);
  const int grow1 = (r1 >> 2) * HD + blk * 4 + (r1 & 3);
  float w0[24], w1[24];
#pragma unroll
  for (int j = 0; j < 24; ++j) {
    w0[j] = Wih[(size_t)grow0 * HD + ks + j];
    w1[j] = Wih[(size_t)grow1 * HD + ks + j];
  }
  if (t < 16) {
    int gr = (t >> 2) * HD + blk * 4 + (t & 3);
    sbias[t] = bih[gr] + bhh[gr];
  }
  float cstate = 0.f;
  const int lane = t & 63, wv = t >> 6, hf = (lane >> 5);

  // one LSTM cell step; publishes packed [tag|fp16(h)] words
  auto do_step = [&](uint32_t* __restrict__ hw_out, int tag,
                     float* __restrict__ hall_row) {
    float acc0[8], acc1[8];
#pragma unroll
    for (int b = 0; b < 8; ++b) { acc0[b] = 0.f; acc1[b] = 0.f; }
#pragma unroll
    for (int b = 0; b < 8; ++b) {
      const float* hb = &h_lds[b * PADH + ks];
#pragma unroll
      for (int j4 = 0; j4 < 6; ++j4) {
        f32x4 hv = *reinterpret_cast<const f32x4*>(hb + j4 * 4);
#pragma unroll
        for (int e = 0; e < 4; ++e) {
          acc0[b] = fmaf(w0[j4 * 4 + e], hv[e], acc0[b]);
          acc1[b] = fmaf(w1[j4 * 4 + e], hv[e], acc1[b]);
        }
      }
    }
    // reduce over the wave's 8 k-slices: 2 swizzle rounds -> per-half sums
#pragma unroll
    for (int b = 0; b < 8; ++b) {
      acc0[b] += swz8(acc0[b]);  acc0[b] += swz16(acc0[b]);
      acc1[b] += swz8(acc1[b]);  acc1[b] += swz16(acc1[b]);
    }
    if ((lane & 31) < 8) {
#pragma unroll
      for (int b = 0; b < 8; ++b) {
        red[wv][hf][r0][b] = acc0[b];
        red[wv][hf][r1][b] = acc1[b];
      }
    }
    __syncthreads();                      // red complete
    if (t < 32) {
      int ul = t >> 3, b = t & 7;
      float gs[4];
#pragma unroll
      for (int g = 0; g < 4; ++g) {
        int r = g * 4 + ul;
        float s = sbias[r];
#pragma unroll
        for (int w2 = 0; w2 < 4; ++w2) s += red[w2][0][r][b] + red[w2][1][r][b];
        gs[g] = s;
      }
      float iv = sigf(gs[0]);
      float fv = sigf(gs[1]);
      float gv = tanhf_fast(gs[2]);
      float ov = sigf(gs[3]);
      cstate = fv * cstate + iv * gv;
      float hn = ov * tanhf_fast(cstate);
      // pack [tag | fp16(hn)] -- single atomic word, publish immediately
      union { _Float16 f; unsigned short u; } cv;
      cv.f = (_Float16)hn;
      st_u32(&hw_out[(blk * 4 + ul) * 8 + b],
             ((uint32_t)tag << 16) | (uint32_t)cv.u);
      if (hall_row) hall_row[(size_t)b * HD + blk * 4 + ul] = hn;  // plain f32
    }
  };

  // pre-step: h1 = cell(cls, 0, 0) -> gates = cls@Wih^T + (bih+bhh)
  for (int i = t; i < 1536; i += 256) {
    int b = i / 192, c4 = i - b * 192;
    *reinterpret_cast<f32x4*>(&h_lds[b * PADH + c4 * 4]) =
        reinterpret_cast<const f32x4*>(cls)[i];
  }
  __syncthreads();
  do_step(hw + 6144, 1, nullptr);        // h_1 -> parity 1, tag 1
  // switch to combined weights W_ih + W_hh (inside the scan, x == h)
#pragma unroll
  for (int j = 0; j < 24; ++j) {
    w0[j] += Whh[(size_t)grow0 * HD + ks + j];
    w1[j] += Whh[(size_t)grow1 * HD + ks + j];
  }
  for (int s = 1; s <= NSTEPS; ++s) {
    // poll own 24 words of h_s (word f: unit=f>>3, batch=f&7); data IS flag
    const uint32_t* src = hw + (s & 1) * 6144;
    uint32_t w[24];
    bool ok;
    do {
      ok = true;
#pragma unroll
      for (int k = 0; k < 24; ++k) {
        w[k] = ld_u32(&src[t + k * 256]);
        if ((w[k] >> 16) != (uint32_t)s) ok = false;
      }
    } while (!ok);
#pragma unroll
    for (int k = 0; k < 24; ++k) {
      int f = t + k * 256;
      union { unsigned short u; _Float16 f16; } cv;
      cv.u = (unsigned short)(w[k] & 0xFFFFu);
      h_lds[(f & 7) * PADH + (f >> 3)] = (float)cv.f16;
    }
    __syncthreads();                     // h_s staged in LDS
    do_step(hw + ((s + 1) & 1) * 6144, s + 1,
            Hall + (size_t)(s - 1) * (8 * HD));
  }
}

// ---------------- head: dense + gelu(erf) + LayerNorm -> T (bf16) ----------
__global__ __launch_bounds__(256) void head_kernel(
    const float* __restrict__ Hall, const float* __restrict__ WdT,
    const float* __restrict__ bd, const float* __restrict__ gamma,
    const float* __restrict__ beta, unsigned short* __restrict__ Tm) {
  __shared__ float hT[HD][16];
  __shared__ float rbuf[4][16];
  __shared__ float mu_s[16], rs_s[16];
  const int t = threadIdx.x;
  const int r0 = blockIdx.x * 16;
  {
    const int row = t & 15, ksl = t >> 4;
    const float* src = Hall + (size_t)(r0 + row) * HD + ksl * 48;
#pragma unroll
    for (int i = 0; i < 12; ++i) {
      f32x4 v = *reinterpret_cast<const f32x4*>(src + i * 4);
      int k = ksl * 48 + i * 4;
      hT[k][row] = v[0]; hT[k + 1][row] = v[1];
      hT[k + 2][row] = v[2]; hT[k + 3][row] = v[3];
    }
  }
  __syncthreads();
  float a0[16], a1[16], a2[16];
#pragma unroll
  for (int r = 0; r < 16; ++r) { a0[r] = 0.f; a1[r] = 0.f; a2[r] = 0.f; }
  for (int k = 0; k < HD; ++k) {
    float wa = WdT[(size_t)k * HD + t];
    float wb = WdT[(size_t)k * HD + t + 256];
    float wc = WdT[(size_t)k * HD + t + 512];
    f32x4 hv4[4];
#pragma unroll
    for (int q = 0; q < 4; ++q)
      hv4[q] = *reinterpret_cast<const f32x4*>(&hT[k][q * 4]);
#pragma unroll
    for (int r = 0; r < 16; ++r) {
      float hv = hv4[r >> 2][r & 3];
      a0[r] = fmaf(wa, hv, a0[r]);
      a1[r] = fmaf(wb, hv, a1[r]);
      a2[r] = fmaf(wc, hv, a2[r]);
    }
  }
  float g0 = gamma[t], g1 = gamma[t + 256], g2 = gamma[t + 512];
  float be0 = beta[t], be1 = beta[t + 256], be2 = beta[t + 512];
  float bd0 = bd[t], bd1 = bd[t + 256], bd2 = bd[t + 512];
#pragma unroll
  for (int r = 0; r < 16; ++r) {
    float x;
    x = a0[r] + bd0; a0[r] = 0.5f * x * (1.f + erff(x * 0.7071067811865476f));
    x = a1[r] + bd1; a1[r] = 0.5f * x * (1.f + erff(x * 0.7071067811865476f));
    x = a2[r] + bd2; a2[r] = 0.5f * x * (1.f + erff(x * 0.7071067811865476f));
  }
  float ps[16];
  const int lane = t & 63, wv = t >> 6;
#pragma unroll
  for (int r = 0; r < 16; ++r) ps[r] = a0[r] + a1[r] + a2[r];
#pragma unroll
  for (int r = 0; r < 16; ++r)
#pragma unroll
    for (int m = 1; m < 64; m <<= 1) ps[r] += __shfl_xor(ps[r], m);
  if (lane == 0) {
#pragma unroll
    for (int r = 0; r < 16; ++r) rbuf[wv][r] = ps[r];
  }
  __syncthreads();
  if (t < 16) mu_s[t] = (rbuf[0][t] + rbuf[1][t] + rbuf[2][t] + rbuf[3][t]) * (1.f / HD);
  __syncthreads();
#pragma unroll
  for (int r = 0; r < 16; ++r) {
    float mu = mu_s[r];
    float d0 = a0[r] - mu, d1 = a1[r] - mu, d2 = a2[r] - mu;
    ps[r] = d0 * d0 + d1 * d1 + d2 * d2;
  }
#pragma unroll
  for (int r = 0; r < 16; ++r)
#pragma unroll
    for (int m = 1; m < 64; m <<= 1) ps[r] += __shfl_xor(ps[r], m);
  if (lane == 0) {
#pragma unroll
    for (int r = 0; r < 16; ++r) rbuf[wv][r] = ps[r];
  }
  __syncthreads();
  if (t < 16)
    rs_s[t] = 1.f / sqrtf((rbuf[0][t] + rbuf[1][t] + rbuf[2][t] + rbuf[3][t]) * (1.f / HD) + 1e-12f);
  __syncthreads();
#pragma unroll
  for (int r = 0; r < 16; ++r) {
    float mu = mu_s[r], rs = rs_s[r];
    size_t ro = (size_t)(r0 + r) * HD;
    Tm[ro + t]       = f2bf((a0[r] - mu) * rs * g0 + be0);
    Tm[ro + t + 256] = f2bf((a1[r] - mu) * rs * g1 + be1);
    Tm[ro + t + 512] = f2bf((a2[r] - mu) * rs * g2 + be2);
  }
}

// ------ decoder GEMM: out = T @ WvB^T + bvoc  (bf16 MFMA, XCD swizzle) ----
__global__ __launch_bounds__(256) void gemm_kernel(
    const unsigned short* __restrict__ Tm, const unsigned short* __restrict__ Wv,
    const float* __restrict__ bvoc, float* __restrict__ out) {
  __shared__ unsigned short As[128 * 64];
  __shared__ unsigned short Bs[128 * 64];
  const int t = threadIdx.x;
  const int lane = t & 63, wid = t >> 6;
  const int wm = wid >> 1, wn = wid & 1;
  // XCD-aware bijective swizzle: nwg = 166*32 = 5312 = 8*664. Dispatch index
  // lid lands on XCD lid%8; give each XCD a contiguous chunk of work ids so
  // neighboring tiles (sharing A/B panels) hit the same L2.
  const int nbx = VOCP / 128;                        // 166
  int lid = blockIdx.y * nbx + blockIdx.x;
  int swz = (lid & 7) * ((nbx * (MPAD / 128)) >> 3) + (lid >> 3);
  const int m0 = (swz / nbx) * 128, n0 = (swz % nbx) * 128;
  const int lrow = lane & 15, lgrp = lane >> 4;
  f32x4 acc[4][4] = {};
  for (int kt = 0; kt < HD; kt += 64) {
#pragma unroll
    for (int it = 0; it < 4; ++it) {
      int slot = it * 256 + t;
      int row = slot >> 3, g = slot & 7;
      int sg = g ^ (row & 7);                       // pre-swizzled source
      const unsigned short* sa = Tm + (size_t)(m0 + row) * HD + kt + sg * 8;
      const unsigned short* sb = Wv + (size_t)(n0 + row) * HD + kt + sg * 8;
      unsigned short* da = &As[(it * 256 + wid * 64) * 8];  // wave-uniform base
      unsigned short* db = &Bs[(it * 256 + wid * 64) * 8];
      gl_lds16(sa, da);
      gl_lds16(sb, db);
    }
    __syncthreads();
#pragma unroll
    for (int kk = 0; kk < 2; ++kk) {
      short8 af[4], bfr[4];
#pragma unroll
      for (int i = 0; i < 4; ++i) {
        int row = wm * 64 + i * 16 + lrow;
        int gg = (kk * 4 + lgrp) ^ (row & 7);       // swizzled read
        af[i] = *reinterpret_cast<const short8*>(&As[row * 64 + gg * 8]);
      }
#pragma unroll
      for (int j = 0; j < 4; ++j) {
        int row = wn * 64 + j * 16 + lrow;
        int gg = (kk * 4 + lgrp) ^ (row & 7);
        bfr[j] = *reinterpret_cast<const short8*>(&Bs[row * 64 + gg * 8]);
      }
#pragma unroll
      for (int i = 0; i < 4; ++i)
#pragma unroll
        for (int j = 0; j < 4; ++j)
          acc[i][j] = __builtin_amdgcn_mfma_f32_16x16x32_bf16(af[i], bfr[j], acc[i][j], 0, 0, 0);
    }
    __syncthreads();
  }
#pragma unroll
  for (int j = 0; j < 4; ++j) {
    int col = n0 + wn * 64 + j * 16 + lrow;
    bool cok = col < VOC;
    float bv = cok ? bvoc[col] : 0.f;
#pragma unroll
    for (int i = 0; i < 4; ++i) {
      int rbase = m0 + wm * 64 + i * 16 + lgrp * 4;
#pragma unroll
      for (int e = 0; e < 4; ++e) {
        int row = rbase + e;
        if (cok && row < MROWS) out[(size_t)row * VOC + col] = acc[i][j][e] + bv;
      }
    }
  }
}

extern "C" void kernel_launch(void* const* d_in, const int* in_sizes, int n_in,
                              void* d_out, int out_size, void* d_ws, size_t ws_size,
                              hipStream_t stream) {
  (void)in_sizes; (void)n_in; (void)out_size; (void)ws_size;
  const float* cls  = (const float*)d_in[0];
  const float* Wih  = (const float*)d_in[1];
  const float* Whh  = (const float*)d_in[2];
  const float* bih  = (const float*)d_in[3];
  const float* bhh  = (const float*)d_in[4];
  const float* Wd   = (const float*)d_in[5];
  const float* bd   = (const float*)d_in[6];
  const float* gmm  = (const float*)d_in[7];
  const float* bet  = (const float*)d_in[8];
  const float* Wv   = (const float*)d_in[9];
  const float* bvoc = (const float*)d_in[10];
  char* ws = (char*)d_ws;
  uint32_t* hw   = (uint32_t*)(ws + OFF_HW);
  float* Hall  = (float*)(ws + OFF_HALL);
  float* WdT   = (float*)(ws + OFF_WDT);
  unsigned short* Tm  = (unsigned short*)(ws + OFF_T);
  unsigned short* WvB = (unsigned short*)(ws + OFF_WV);
  float* out = (float*)d_out;

  hipLaunchKernelGGL(prep_kernel, dim3(4096), dim3(256), 0, stream, Wd, WdT, Wv, WvB, hw);
  hipLaunchKernelGGL(lstm_kernel, dim3(NBL), dim3(256), 0, stream,
                     cls, Wih, Whh, bih, bhh, hw, Hall);
  hipLaunchKernelGGL(head_kernel, dim3(MPAD / 16), dim3(256), 0, stream,
                     Hall, WdT, bd, gmm, bet, Tm);
  hipLaunchKernelGGL(gemm_kernel, dim3(VOCP / 128, MPAD / 128), dim3(256), 0, stream,
                     Tm, WvB, bvoc, out);
}

// Round 14
// 2068.466 us; speedup vs baseline: 4.7554x; 1.0432x over previous
//
#include <hip/hip_runtime.h>
#include <hip/hip_bf16.h>
#include <cstdint>

#define HD 768
#define VOC 21128
#define VOCP 21248
#define NSTEPS 511
#define MROWS 4088      // 511*8
#define MPAD 4096
#define NBL 192         // lstm blocks (co-resident, 192 < 256 CUs)

typedef float f32x4 __attribute__((ext_vector_type(4)));
typedef short short8 __attribute__((ext_vector_type(8)));

// ---- workspace layout (bytes) ----
// 0        : (unused)                                                (768)
// 768      : hw[2][6144] u32  packed h words [tag16|fp16], [u][b]    (49152)
// 49920    : HallB[4096][768] bf16 (rows >=4088 never written)       (6291456)
// 6341376  : DT[4096][768] bf16  (head dense out, then LN'd in place)(6291456)
// 12632832 : WdB[768][768] bf16  (W_dense, row-major [out][in])      (1179648)
// 13812480 : WvB[21248][768] bf16                                    (32636928) -> end 46449408
#define OFF_HW    768
#define OFF_HALLB 49920ULL
#define OFF_DT    6341376ULL
#define OFF_WDB   12632832ULL
#define OFF_WV    13812480ULL
#define PADH 772        // h_lds row stride (bank-conflict pad)

__device__ __forceinline__ unsigned short f2bf(float x) {
  unsigned u = __float_as_uint(x);
  u += 0x7FFFu + ((u >> 16) & 1u);   // RNE
  return (unsigned short)(u >> 16);
}
__device__ __forceinline__ float bf2f(unsigned short u) {
  return __uint_as_float(((unsigned)u) << 16);
}

__device__ __forceinline__ void gl_lds16(const void* g, void* l) {
  __builtin_amdgcn_global_load_lds(
      (const __attribute__((address_space(1))) void*)g,
      (__attribute__((address_space(3))) void*)l, 16, 0, 0);
}

// relaxed agent-scope (sc1): coherent-point traffic, no cache-wide ops
__device__ __forceinline__ void st_u32(uint32_t* p, uint32_t v) {
  __hip_atomic_store(p, v, __ATOMIC_RELAXED, __HIP_MEMORY_SCOPE_AGENT);
}
__device__ __forceinline__ uint32_t ld_u32(const uint32_t* p) {
  return __hip_atomic_load(p, __ATOMIC_RELAXED, __HIP_MEMORY_SCOPE_AGENT);
}

// wave-local xor-swizzles (within 32-lane halves; BitMode patterns)
__device__ __forceinline__ float swz8(float x) {
  return __int_as_float(__builtin_amdgcn_ds_swizzle(__float_as_int(x), 0x201F));
}
__device__ __forceinline__ float swz16(float x) {
  return __int_as_float(__builtin_amdgcn_ds_swizzle(__float_as_int(x), 0x401F));
}

// overflow-safe fast activations (rcp(inf)=0 gives exact saturation)
__device__ __forceinline__ float sigf(float x) {
  return __builtin_amdgcn_rcpf(1.f + __expf(-x));
}
__device__ __forceinline__ float tanhf_fast(float x) {
  float ax = fabsf(x);
  float e = __expf(-2.f * ax);                       // in (0,1], no overflow
  float t = (1.f - e) * __builtin_amdgcn_rcpf(1.f + e);
  return copysignf(t, x);
}

// ------- prep: Wd->bf16 (no transpose: [out][in]), Wv->bf16, hw zero ------
__global__ __launch_bounds__(256) void prep_kernel(
    const float* __restrict__ Wd, unsigned short* __restrict__ WdB,
    const float* __restrict__ Wv, unsigned short* __restrict__ WvB,
    uint32_t* __restrict__ hw) {
  unsigned idx = blockIdx.x * 256 + threadIdx.x;
  unsigned stride = gridDim.x * 256;
  for (unsigned i = idx; i < 12288; i += stride) hw[i] = 0;   // stale-tag kill
  for (unsigned i = idx; i < HD * HD; i += stride) WdB[i] = f2bf(Wd[i]);
  const unsigned NV = (unsigned)VOCP * HD, NVr = (unsigned)VOC * HD;
  for (unsigned i = idx; i < NV; i += stride)
    WvB[i] = f2bf(i < NVr ? Wv[i] : 0.f);
}

// ------ lstm: persistent, 192 blocks, self-validating word protocol -------
// (round-7 configuration: global best, 1734 us measured; Hall now bf16)
__global__ __launch_bounds__(256) void lstm_kernel(
    const float* __restrict__ cls, const float* __restrict__ Wih,
    const float* __restrict__ Whh, const float* __restrict__ bih,
    const float* __restrict__ bhh, uint32_t* __restrict__ hw,
    unsigned short* __restrict__ HallB) {
  __shared__ float h_lds[8 * PADH];       // current h (or cls), [b][u] padded
  __shared__ float red[4][2][16][8];      // [wave][half][row][b] partials
  __shared__ float sbias[16];             // combined gate biases, local rows
  const int t = threadIdx.x;
  const int blk = blockIdx.x;
  const int p_ = t & 7;                // row-pair 0..7 (16 rows/block)
  const int s_ = t >> 3;               // k-slice 0..31 (24 k each)
  const int ks = s_ * 24;
  const int r0 = 2 * p_, r1 = r0 + 1;  // local rows; gate=r>>2, unit=r&3
  const int grow0 = (r0 >> 2) * HD + blk * 4 + (r0 & 3);
  const int grow1 = (r1 >> 2) * HD + blk * 4 + (r1 & 3);
  float w0[24], w1[24];
#pragma unroll
  for (int j = 0; j < 24; ++j) {
    w0[j] = Wih[(size_t)grow0 * HD + ks + j];
    w1[j] = Wih[(size_t)grow1 * HD + ks + j];
  }
  if (t < 16) {
    int gr = (t >> 2) * HD + blk * 4 + (t & 3);
    sbias[t] = bih[gr] + bhh[gr];
  }
  float cstate = 0.f;
  const int lane = t & 63, wv = t >> 6, hf = (lane >> 5);

  // one LSTM cell step; publishes packed [tag|fp16(h)] words
  auto do_step = [&](uint32_t* __restrict__ hw_out, int tag,
                     unsigned short* __restrict__ hall_row) {
    float acc0[8], acc1[8];
#pragma unroll
    for (int b = 0; b < 8; ++b) { acc0[b] = 0.f; acc1[b] = 0.f; }
#pragma unroll
    for (int b = 0; b < 8; ++b) {
      const float* hb = &h_lds[b * PADH + ks];
#pragma unroll
      for (int j4 = 0; j4 < 6; ++j4) {
        f32x4 hv = *reinterpret_cast<const f32x4*>(hb + j4 * 4);
#pragma unroll
        for (int e = 0; e < 4; ++e) {
          acc0[b] = fmaf(w0[j4 * 4 + e], hv[e], acc0[b]);
          acc1[b] = fmaf(w1[j4 * 4 + e], hv[e], acc1[b]);
        }
      }
    }
    // reduce over the wave's 8 k-slices: 2 swizzle rounds -> per-half sums
#pragma unroll
    for (int b = 0; b < 8; ++b) {
      acc0[b] += swz8(acc0[b]);  acc0[b] += swz16(acc0[b]);
      acc1[b] += swz8(acc1[b]);  acc1[b] += swz16(acc1[b]);
    }
    if ((lane & 31) < 8) {
#pragma unroll
      for (int b = 0; b < 8; ++b) {
        red[wv][hf][r0][b] = acc0[b];
        red[wv][hf][r1][b] = acc1[b];
      }
    }
    __syncthreads();                      // red complete
    if (t < 32) {
      int ul = t >> 3, b = t & 7;
      float gs[4];
#pragma unroll
      for (int g = 0; g < 4; ++g) {
        int r = g * 4 + ul;
        float s = sbias[r];
#pragma unroll
        for (int w2 = 0; w2 < 4; ++w2) s += red[w2][0][r][b] + red[w2][1][r][b];
        gs[g] = s;
      }
      float iv = sigf(gs[0]);
      float fv = sigf(gs[1]);
      float gv = tanhf_fast(gs[2]);
      float ov = sigf(gs[3]);
      cstate = fv * cstate + iv * gv;
      float hn = ov * tanhf_fast(cstate);
      // pack [tag | fp16(hn)] -- single atomic word, publish immediately
      union { _Float16 f; unsigned short u; } cv;
      cv.f = (_Float16)hn;
      st_u32(&hw_out[(blk * 4 + ul) * 8 + b],
             ((uint32_t)tag << 16) | (uint32_t)cv.u);
      if (hall_row) hall_row[(size_t)b * HD + blk * 4 + ul] = f2bf(hn);
    }
  };

  // pre-step: h1 = cell(cls, 0, 0) -> gates = cls@Wih^T + (bih+bhh)
  for (int i = t; i < 1536; i += 256) {
    int b = i / 192, c4 = i - b * 192;
    *reinterpret_cast<f32x4*>(&h_lds[b * PADH + c4 * 4]) =
        reinterpret_cast<const f32x4*>(cls)[i];
  }
  __syncthreads();
  do_step(hw + 6144, 1, nullptr);        // h_1 -> parity 1, tag 1
  // switch to combined weights W_ih + W_hh (inside the scan, x == h)
#pragma unroll
  for (int j = 0; j < 24; ++j) {
    w0[j] += Whh[(size_t)grow0 * HD + ks + j];
    w1[j] += Whh[(size_t)grow1 * HD + ks + j];
  }
  for (int s = 1; s <= NSTEPS; ++s) {
    // poll own 24 words of h_s (word f: unit=f>>3, batch=f&7); data IS flag
    const uint32_t* src = hw + (s & 1) * 6144;
    uint32_t w[24];
    bool ok;
    do {
      ok = true;
#pragma unroll
      for (int k = 0; k < 24; ++k) {
        w[k] = ld_u32(&src[t + k * 256]);
        if ((w[k] >> 16) != (uint32_t)s) ok = false;
      }
    } while (!ok);
#pragma unroll
    for (int k = 0; k < 24; ++k) {
      int f = t + k * 256;
      union { unsigned short u; _Float16 f16; } cv;
      cv.u = (unsigned short)(w[k] & 0xFFFFu);
      h_lds[(f & 7) * PADH + (f >> 3)] = (float)cv.f16;
    }
    __syncthreads();                     // h_s staged in LDS
    do_step(hw + ((s + 1) & 1) * 6144, s + 1,
            HallB + (size_t)(s - 1) * (8 * HD));
  }
}

// ---- head dense (MFMA): D = gelu(HallB @ WdB^T + bd), bf16 out ----------
__global__ __launch_bounds__(256) void head_mm_kernel(
    const unsigned short* __restrict__ Ha, const unsigned short* __restrict__ Wb,
    const float* __restrict__ bd, unsigned short* __restrict__ DT) {
  __shared__ unsigned short As[128 * 64];
  __shared__ unsigned short Bs[128 * 64];
  const int t = threadIdx.x;
  const int lane = t & 63, wid = t >> 6;
  const int wm = wid >> 1, wn = wid & 1;
  const int m0 = blockIdx.y * 128, n0 = blockIdx.x * 128;   // n0 <= 640
  const int lrow = lane & 15, lgrp = lane >> 4;
  f32x4 acc[4][4] = {};
  for (int kt = 0; kt < HD; kt += 64) {
#pragma unroll
    for (int it = 0; it < 4; ++it) {
      int slot = it * 256 + t;
      int row = slot >> 3, g = slot & 7;
      int sg = g ^ (row & 7);                       // pre-swizzled source
      const unsigned short* sa = Ha + (size_t)(m0 + row) * HD + kt + sg * 8;
      const unsigned short* sb = Wb + (size_t)(n0 + row) * HD + kt + sg * 8;
      unsigned short* da = &As[(it * 256 + wid * 64) * 8];  // wave-uniform base
      unsigned short* db = &Bs[(it * 256 + wid * 64) * 8];
      gl_lds16(sa, da);
      gl_lds16(sb, db);
    }
    __syncthreads();
#pragma unroll
    for (int kk = 0; kk < 2; ++kk) {
      short8 af[4], bfr[4];
#pragma unroll
      for (int i = 0; i < 4; ++i) {
        int row = wm * 64 + i * 16 + lrow;
        int gg = (kk * 4 + lgrp) ^ (row & 7);       // swizzled read
        af[i] = *reinterpret_cast<const short8*>(&As[row * 64 + gg * 8]);
      }
#pragma unroll
      for (int j = 0; j < 4; ++j) {
        int row = wn * 64 + j * 16 + lrow;
        int gg = (kk * 4 + lgrp) ^ (row & 7);
        bfr[j] = *reinterpret_cast<const short8*>(&Bs[row * 64 + gg * 8]);
      }
#pragma unroll
      for (int i = 0; i < 4; ++i)
#pragma unroll
        for (int j = 0; j < 4; ++j)
          acc[i][j] = __builtin_amdgcn_mfma_f32_16x16x32_bf16(af[i], bfr[j], acc[i][j], 0, 0, 0);
    }
    __syncthreads();
  }
#pragma unroll
  for (int j = 0; j < 4; ++j) {
    int col = n0 + wn * 64 + j * 16 + lrow;        // < 768 always
    float bv = bd[col];
#pragma unroll
    for (int i = 0; i < 4; ++i) {
      int rbase = m0 + wm * 64 + i * 16 + lgrp * 4;
#pragma unroll
      for (int e = 0; e < 4; ++e) {
        int row = rbase + e;
        if (row < MROWS) {
          float x = acc[i][j][e] + bv;
          float g = 0.5f * x * (1.f + erff(x * 0.7071067811865476f));
          DT[(size_t)row * HD + col] = f2bf(g);
        }
      }
    }
  }
}

// ---- LayerNorm in place: T = LN(D)*gamma+beta (bf16 -> bf16) -------------
__global__ __launch_bounds__(256) void ln_kernel(
    unsigned short* __restrict__ DT, const float* __restrict__ gamma,
    const float* __restrict__ beta) {
  __shared__ float rbuf[4][16];
  __shared__ float mu_s[16], rs_s[16];
  const int t = threadIdx.x;
  const int r0 = blockIdx.x * 16;
  float a0[16], a1[16], a2[16];
#pragma unroll
  for (int r = 0; r < 16; ++r) {
    size_t ro = (size_t)(r0 + r) * HD;
    a0[r] = bf2f(DT[ro + t]);
    a1[r] = bf2f(DT[ro + t + 256]);
    a2[r] = bf2f(DT[ro + t + 512]);
  }
  float g0 = gamma[t], g1 = gamma[t + 256], g2 = gamma[t + 512];
  float be0 = beta[t], be1 = beta[t + 256], be2 = beta[t + 512];
  float ps[16];
  const int lane = t & 63, wv = t >> 6;
#pragma unroll
  for (int r = 0; r < 16; ++r) ps[r] = a0[r] + a1[r] + a2[r];
#pragma unroll
  for (int r = 0; r < 16; ++r)
#pragma unroll
    for (int m = 1; m < 64; m <<= 1) ps[r] += __shfl_xor(ps[r], m);
  if (lane == 0) {
#pragma unroll
    for (int r = 0; r < 16; ++r) rbuf[wv][r] = ps[r];
  }
  __syncthreads();
  if (t < 16) mu_s[t] = (rbuf[0][t] + rbuf[1][t] + rbuf[2][t] + rbuf[3][t]) * (1.f / HD);
  __syncthreads();
#pragma unroll
  for (int r = 0; r < 16; ++r) {
    float mu = mu_s[r];
    float d0 = a0[r] - mu, d1 = a1[r] - mu, d2 = a2[r] - mu;
    ps[r] = d0 * d0 + d1 * d1 + d2 * d2;
  }
#pragma unroll
  for (int r = 0; r < 16; ++r)
#pragma unroll
    for (int m = 1; m < 64; m <<= 1) ps[r] += __shfl_xor(ps[r], m);
  if (lane == 0) {
#pragma unroll
    for (int r = 0; r < 16; ++r) rbuf[wv][r] = ps[r];
  }
  __syncthreads();
  if (t < 16)
    rs_s[t] = 1.f / sqrtf((rbuf[0][t] + rbuf[1][t] + rbuf[2][t] + rbuf[3][t]) * (1.f / HD) + 1e-12f);
  __syncthreads();
#pragma unroll
  for (int r = 0; r < 16; ++r) {
    float mu = mu_s[r], rs = rs_s[r];
    size_t ro = (size_t)(r0 + r) * HD;
    DT[ro + t]       = f2bf((a0[r] - mu) * rs * g0 + be0);
    DT[ro + t + 256] = f2bf((a1[r] - mu) * rs * g1 + be1);
    DT[ro + t + 512] = f2bf((a2[r] - mu) * rs * g2 + be2);
  }
}

// ------ decoder GEMM: out = T @ WvB^T + bvoc  (bf16 MFMA, XCD swizzle) ----
__global__ __launch_bounds__(256) void gemm_kernel(
    const unsigned short* __restrict__ Tm, const unsigned short* __restrict__ Wv,
    const float* __restrict__ bvoc, float* __restrict__ out) {
  __shared__ unsigned short As[128 * 64];
  __shared__ unsigned short Bs[128 * 64];
  const int t = threadIdx.x;
  const int lane = t & 63, wid = t >> 6;
  const int wm = wid >> 1, wn = wid & 1;
  // XCD-aware bijective swizzle: nwg = 166*32 = 5312 = 8*664.
  const int nbx = VOCP / 128;                        // 166
  int lid = blockIdx.y * nbx + blockIdx.x;
  int swz = (lid & 7) * ((nbx * (MPAD / 128)) >> 3) + (lid >> 3);
  const int m0 = (swz / nbx) * 128, n0 = (swz % nbx) * 128;
  const int lrow = lane & 15, lgrp = lane >> 4;
  f32x4 acc[4][4] = {};
  for (int kt = 0; kt < HD; kt += 64) {
#pragma unroll
    for (int it = 0; it < 4; ++it) {
      int slot = it * 256 + t;
      int row = slot >> 3, g = slot & 7;
      int sg = g ^ (row & 7);                       // pre-swizzled source
      const unsigned short* sa = Tm + (size_t)(m0 + row) * HD + kt + sg * 8;
      const unsigned short* sb = Wv + (size_t)(n0 + row) * HD + kt + sg * 8;
      unsigned short* da = &As[(it * 256 + wid * 64) * 8];  // wave-uniform base
      unsigned short* db = &Bs[(it * 256 + wid * 64) * 8];
      gl_lds16(sa, da);
      gl_lds16(sb, db);
    }
    __syncthreads();
#pragma unroll
    for (int kk = 0; kk < 2; ++kk) {
      short8 af[4], bfr[4];
#pragma unroll
      for (int i = 0; i < 4; ++i) {
        int row = wm * 64 + i * 16 + lrow;
        int gg = (kk * 4 + lgrp) ^ (row & 7);       // swizzled read
        af[i] = *reinterpret_cast<const short8*>(&As[row * 64 + gg * 8]);
      }
#pragma unroll
      for (int j = 0; j < 4; ++j) {
        int row = wn * 64 + j * 16 + lrow;
        int gg = (kk * 4 + lgrp) ^ (row & 7);
        bfr[j] = *reinterpret_cast<const short8*>(&Bs[row * 64 + gg * 8]);
      }
#pragma unroll
      for (int i = 0; i < 4; ++i)
#pragma unroll
        for (int j = 0; j < 4; ++j)
          acc[i][j] = __builtin_amdgcn_mfma_f32_16x16x32_bf16(af[i], bfr[j], acc[i][j], 0, 0, 0);
    }
    __syncthreads();
  }
#pragma unroll
  for (int j = 0; j < 4; ++j) {
    int col = n0 + wn * 64 + j * 16 + lrow;
    bool cok = col < VOC;
    float bv = cok ? bvoc[col] : 0.f;
#pragma unroll
    for (int i = 0; i < 4; ++i) {
      int rbase = m0 + wm * 64 + i * 16 + lgrp * 4;
#pragma unroll
      for (int e = 0; e < 4; ++e) {
        int row = rbase + e;
        if (cok && row < MROWS) out[(size_t)row * VOC + col] = acc[i][j][e] + bv;
      }
    }
  }
}

extern "C" void kernel_launch(void* const* d_in, const int* in_sizes, int n_in,
                              void* d_out, int out_size, void* d_ws, size_t ws_size,
                              hipStream_t stream) {
  (void)in_sizes; (void)n_in; (void)out_size; (void)ws_size;
  const float* cls  = (const float*)d_in[0];
  const float* Wih  = (const float*)d_in[1];
  const float* Whh  = (const float*)d_in[2];
  const float* bih  = (const float*)d_in[3];
  const float* bhh  = (const float*)d_in[4];
  const float* Wd   = (const float*)d_in[5];
  const float* bd   = (const float*)d_in[6];
  const float* gmm  = (const float*)d_in[7];
  const float* bet  = (const float*)d_in[8];
  const float* Wv   = (const float*)d_in[9];
  const float* bvoc = (const float*)d_in[10];
  char* ws = (char*)d_ws;
  uint32_t* hw = (uint32_t*)(ws + OFF_HW);
  unsigned short* HallB = (unsigned short*)(ws + OFF_HALLB);
  unsigned short* DT    = (unsigned short*)(ws + OFF_DT);
  unsigned short* WdB   = (unsigned short*)(ws + OFF_WDB);
  unsigned short* WvB   = (unsigned short*)(ws + OFF_WV);
  float* out = (float*)d_out;

  hipLaunchKernelGGL(prep_kernel, dim3(4096), dim3(256), 0, stream, Wd, WdB, Wv, WvB, hw);
  hipLaunchKernelGGL(lstm_kernel, dim3(NBL), dim3(256), 0, stream,
                     cls, Wih, Whh, bih, bhh, hw, HallB);
  hipLaunchKernelGGL(head_mm_kernel, dim3(HD / 128, MPAD / 128), dim3(256), 0, stream,
                     HallB, WdB, bd, DT);
  hipLaunchKernelGGL(ln_kernel, dim3(MPAD / 16), dim3(256), 0, stream,
                     DT, gmm, bet);
  hipLaunchKernelGGL(gemm_kernel, dim3(VOCP / 128, MPAD / 128), dim3(256), 0, stream,
                     DT, WvB, bvoc, out);
}

// Round 15
// 2054.674 us; speedup vs baseline: 4.7873x; 1.0067x over previous
//
#include <hip/hip_runtime.h>
#include <hip/hip_bf16.h>
#include <cstdint>

#define HD 768
#define VOC 21128
#define VOCP 21248
#define NSTEPS 511
#define MROWS 4088      // 511*8
#define MPAD 4096
#define NBL 192         // lstm blocks (co-resident, 192 < 256 CUs)

typedef float f32x4 __attribute__((ext_vector_type(4)));
typedef short short8 __attribute__((ext_vector_type(8)));

// ---- workspace layout (bytes) ----
// 0        : (unused)                                                (768)
// 768      : hw[2][6144] u32  packed h words [tag16|fp16], [u][b]    (49152)
// 49920    : HallB[4096][768] bf16 (rows >=4088 never written)       (6291456)
// 6341376  : DT[4096][768] bf16  (head dense out, then LN'd in place)(6291456)
// 12632832 : WdB[768][768] bf16  (W_dense, row-major [out][in])      (1179648)
// 13812480 : WvB[21248][768] bf16                                    (32636928) -> end 46449408
#define OFF_HW    768
#define OFF_HALLB 49920ULL
#define OFF_DT    6341376ULL
#define OFF_WDB   12632832ULL
#define OFF_WV    13812480ULL
#define PADH 772        // h_lds row stride (bank-conflict pad)

__device__ __forceinline__ unsigned short f2bf(float x) {
  unsigned u = __float_as_uint(x);
  u += 0x7FFFu + ((u >> 16) & 1u);   // RNE
  return (unsigned short)(u >> 16);
}
__device__ __forceinline__ float bf2f(unsigned short u) {
  return __uint_as_float(((unsigned)u) << 16);
}

__device__ __forceinline__ void gl_lds16(const void* g, void* l) {
  __builtin_amdgcn_global_load_lds(
      (const __attribute__((address_space(1))) void*)g,
      (__attribute__((address_space(3))) void*)l, 16, 0, 0);
}

// relaxed agent-scope (sc1): coherent-point traffic, no cache-wide ops
__device__ __forceinline__ void st_u32(uint32_t* p, uint32_t v) {
  __hip_atomic_store(p, v, __ATOMIC_RELAXED, __HIP_MEMORY_SCOPE_AGENT);
}
__device__ __forceinline__ uint32_t ld_u32(const uint32_t* p) {
  return __hip_atomic_load(p, __ATOMIC_RELAXED, __HIP_MEMORY_SCOPE_AGENT);
}

// wave-local xor-swizzles (within 32-lane halves; BitMode patterns)
__device__ __forceinline__ float swz8(float x) {
  return __int_as_float(__builtin_amdgcn_ds_swizzle(__float_as_int(x), 0x201F));
}
__device__ __forceinline__ float swz16(float x) {
  return __int_as_float(__builtin_amdgcn_ds_swizzle(__float_as_int(x), 0x401F));
}

// overflow-safe fast activations (rcp(inf)=0 gives exact saturation)
__device__ __forceinline__ float sigf(float x) {
  return __builtin_amdgcn_rcpf(1.f + __expf(-x));
}
__device__ __forceinline__ float tanhf_fast(float x) {
  float ax = fabsf(x);
  float e = __expf(-2.f * ax);                       // in (0,1], no overflow
  float t = (1.f - e) * __builtin_amdgcn_rcpf(1.f + e);
  return copysignf(t, x);
}

// ---------------- zero_hw: stale-tag kill (must precede lstm) -------------
__global__ __launch_bounds__(256) void zero_hw_kernel(uint32_t* __restrict__ hw) {
  hw[blockIdx.x * 256 + threadIdx.x] = 0;     // grid 48 x 256 = 12288
}

// ------ lstm: persistent; blocks 0..191 = r7 protocol (1734us floor);
//        blocks 192..255 = weight bf16 conversion (hidden in lstm window) --
__global__ __launch_bounds__(256) void lstm_kernel(
    const float* __restrict__ cls, const float* __restrict__ Wih,
    const float* __restrict__ Whh, const float* __restrict__ bih,
    const float* __restrict__ bhh, uint32_t* __restrict__ hw,
    unsigned short* __restrict__ HallB,
    const float* __restrict__ Wd, unsigned short* __restrict__ WdB,
    const float* __restrict__ Wv, unsigned short* __restrict__ WvB) {
  const int t = threadIdx.x;
  if (blockIdx.x >= NBL) {
    // conversion role: no dependency on/from lstm blocks (stream-order
    // guarantees consumers head_mm/gemm run after this kernel completes)
    unsigned idx = (blockIdx.x - NBL) * 256 + t;
    const unsigned stride = 64 * 256;
    for (unsigned i = idx; i < HD * HD; i += stride) WdB[i] = f2bf(Wd[i]);
    const unsigned NV = (unsigned)VOCP * HD, NVr = (unsigned)VOC * HD;
    for (unsigned i = idx; i < NV; i += stride)
      WvB[i] = f2bf(i < NVr ? Wv[i] : 0.f);
    return;
  }
  __shared__ float h_lds[8 * PADH];       // current h (or cls), [b][u] padded
  __shared__ float red[4][2][16][8];      // [wave][half][row][b] partials
  __shared__ float sbias[16];             // combined gate biases, local rows
  const int blk = blockIdx.x;
  const int p_ = t & 7;                // row-pair 0..7 (16 rows/block)
  const int s_ = t >> 3;               // k-slice 0..31 (24 k each)
  const int ks = s_ * 24;
  const int r0 = 2 * p_, r1 = r0 + 1;  // local rows; gate=r>>2, unit=r&3
  const int grow0 = (r0 >> 2) * HD + blk * 4 + (r0 & 3);
  const int grow1 = (r1 >> 2) * HD + blk * 4 + (r1 & 3);
  float w0[24], w1[24];
#pragma unroll
  for (int j = 0; j < 24; ++j) {
    w0[j] = Wih[(size_t)grow0 * HD + ks + j];
    w1[j] = Wih[(size_t)grow1 * HD + ks + j];
  }
  if (t < 16) {
    int gr = (t >> 2) * HD + blk * 4 + (t & 3);
    sbias[t] = bih[gr] + bhh[gr];
  }
  float cstate = 0.f;
  const int lane = t & 63, wv = t >> 6, hf = (lane >> 5);

  // one LSTM cell step; publishes packed [tag|fp16(h)] words
  auto do_step = [&](uint32_t* __restrict__ hw_out, int tag,
                     unsigned short* __restrict__ hall_row) {
    float acc0[8], acc1[8];
#pragma unroll
    for (int b = 0; b < 8; ++b) { acc0[b] = 0.f; acc1[b] = 0.f; }
#pragma unroll
    for (int b = 0; b < 8; ++b) {
      const float* hb = &h_lds[b * PADH + ks];
#pragma unroll
      for (int j4 = 0; j4 < 6; ++j4) {
        f32x4 hv = *reinterpret_cast<const f32x4*>(hb + j4 * 4);
#pragma unroll
        for (int e = 0; e < 4; ++e) {
          acc0[b] = fmaf(w0[j4 * 4 + e], hv[e], acc0[b]);
          acc1[b] = fmaf(w1[j4 * 4 + e], hv[e], acc1[b]);
        }
      }
    }
    // reduce over the wave's 8 k-slices: 2 swizzle rounds -> per-half sums
#pragma unroll
    for (int b = 0; b < 8; ++b) {
      acc0[b] += swz8(acc0[b]);  acc0[b] += swz16(acc0[b]);
      acc1[b] += swz8(acc1[b]);  acc1[b] += swz16(acc1[b]);
    }
    if ((lane & 31) < 8) {
#pragma unroll
      for (int b = 0; b < 8; ++b) {
        red[wv][hf][r0][b] = acc0[b];
        red[wv][hf][r1][b] = acc1[b];
      }
    }
    __syncthreads();                      // red complete
    if (t < 32) {
      int ul = t >> 3, b = t & 7;
      float gs[4];
#pragma unroll
      for (int g = 0; g < 4; ++g) {
        int r = g * 4 + ul;
        float s = sbias[r];
#pragma unroll
        for (int w2 = 0; w2 < 4; ++w2) s += red[w2][0][r][b] + red[w2][1][r][b];
        gs[g] = s;
      }
      float iv = sigf(gs[0]);
      float fv = sigf(gs[1]);
      float gv = tanhf_fast(gs[2]);
      float ov = sigf(gs[3]);
      cstate = fv * cstate + iv * gv;
      float hn = ov * tanhf_fast(cstate);
      // pack [tag | fp16(hn)] -- single atomic word, publish immediately
      union { _Float16 f; unsigned short u; } cv;
      cv.f = (_Float16)hn;
      st_u32(&hw_out[(blk * 4 + ul) * 8 + b],
             ((uint32_t)tag << 16) | (uint32_t)cv.u);
      if (hall_row) hall_row[(size_t)b * HD + blk * 4 + ul] = f2bf(hn);
    }
  };

  // pre-step: h1 = cell(cls, 0, 0) -> gates = cls@Wih^T + (bih+bhh)
  for (int i = t; i < 1536; i += 256) {
    int b = i / 192, c4 = i - b * 192;
    *reinterpret_cast<f32x4*>(&h_lds[b * PADH + c4 * 4]) =
        reinterpret_cast<const f32x4*>(cls)[i];
  }
  __syncthreads();
  do_step(hw + 6144, 1, nullptr);        // h_1 -> parity 1, tag 1
  // switch to combined weights W_ih + W_hh (inside the scan, x == h)
#pragma unroll
  for (int j = 0; j < 24; ++j) {
    w0[j] += Whh[(size_t)grow0 * HD + ks + j];
    w1[j] += Whh[(size_t)grow1 * HD + ks + j];
  }
  for (int s = 1; s <= NSTEPS; ++s) {
    // poll own 24 words of h_s (word f: unit=f>>3, batch=f&7); data IS flag
    const uint32_t* src = hw + (s & 1) * 6144;
    uint32_t w[24];
    bool ok;
    do {
      ok = true;
#pragma unroll
      for (int k = 0; k < 24; ++k) {
        w[k] = ld_u32(&src[t + k * 256]);
        if ((w[k] >> 16) != (uint32_t)s) ok = false;
      }
    } while (!ok);
#pragma unroll
    for (int k = 0; k < 24; ++k) {
      int f = t + k * 256;
      union { unsigned short u; _Float16 f16; } cv;
      cv.u = (unsigned short)(w[k] & 0xFFFFu);
      h_lds[(f & 7) * PADH + (f >> 3)] = (float)cv.f16;
    }
    __syncthreads();                     // h_s staged in LDS
    do_step(hw + ((s + 1) & 1) * 6144, s + 1,
            HallB + (size_t)(s - 1) * (8 * HD));
  }
}

// ---- head dense (MFMA): D = gelu(HallB @ WdB^T + bd), bf16 out ----------
__global__ __launch_bounds__(256) void head_mm_kernel(
    const unsigned short* __restrict__ Ha, const unsigned short* __restrict__ Wb,
    const float* __restrict__ bd, unsigned short* __restrict__ DT) {
  __shared__ unsigned short As[128 * 64];
  __shared__ unsigned short Bs[128 * 64];
  const int t = threadIdx.x;
  const int lane = t & 63, wid = t >> 6;
  const int wm = wid >> 1, wn = wid & 1;
  const int m0 = blockIdx.y * 128, n0 = blockIdx.x * 128;   // n0 <= 640
  const int lrow = lane & 15, lgrp = lane >> 4;
  f32x4 acc[4][4] = {};
  for (int kt = 0; kt < HD; kt += 64) {
#pragma unroll
    for (int it = 0; it < 4; ++it) {
      int slot = it * 256 + t;
      int row = slot >> 3, g = slot & 7;
      int sg = g ^ (row & 7);                       // pre-swizzled source
      const unsigned short* sa = Ha + (size_t)(m0 + row) * HD + kt + sg * 8;
      const unsigned short* sb = Wb + (size_t)(n0 + row) * HD + kt + sg * 8;
      unsigned short* da = &As[(it * 256 + wid * 64) * 8];  // wave-uniform base
      unsigned short* db = &Bs[(it * 256 + wid * 64) * 8];
      gl_lds16(sa, da);
      gl_lds16(sb, db);
    }
    __syncthreads();
#pragma unroll
    for (int kk = 0; kk < 2; ++kk) {
      short8 af[4], bfr[4];
#pragma unroll
      for (int i = 0; i < 4; ++i) {
        int row = wm * 64 + i * 16 + lrow;
        int gg = (kk * 4 + lgrp) ^ (row & 7);       // swizzled read
        af[i] = *reinterpret_cast<const short8*>(&As[row * 64 + gg * 8]);
      }
#pragma unroll
      for (int j = 0; j < 4; ++j) {
        int row = wn * 64 + j * 16 + lrow;
        int gg = (kk * 4 + lgrp) ^ (row & 7);
        bfr[j] = *reinterpret_cast<const short8*>(&Bs[row * 64 + gg * 8]);
      }
#pragma unroll
      for (int i = 0; i < 4; ++i)
#pragma unroll
        for (int j = 0; j < 4; ++j)
          acc[i][j] = __builtin_amdgcn_mfma_f32_16x16x32_bf16(af[i], bfr[j], acc[i][j], 0, 0, 0);
    }
    __syncthreads();
  }
#pragma unroll
  for (int j = 0; j < 4; ++j) {
    int col = n0 + wn * 64 + j * 16 + lrow;        // < 768 always
    float bv = bd[col];
#pragma unroll
    for (int i = 0; i < 4; ++i) {
      int rbase = m0 + wm * 64 + i * 16 + lgrp * 4;
#pragma unroll
      for (int e = 0; e < 4; ++e) {
        int row = rbase + e;
        if (row < MROWS) {
          float x = acc[i][j][e] + bv;
          float g = 0.5f * x * (1.f + erff(x * 0.7071067811865476f));
          DT[(size_t)row * HD + col] = f2bf(g);
        }
      }
    }
  }
}

// ---- LayerNorm in place: T = LN(D)*gamma+beta (bf16 -> bf16) -------------
__global__ __launch_bounds__(256) void ln_kernel(
    unsigned short* __restrict__ DT, const float* __restrict__ gamma,
    const float* __restrict__ beta) {
  __shared__ float rbuf[4][16];
  __shared__ float mu_s[16], rs_s[16];
  const int t = threadIdx.x;
  const int r0 = blockIdx.x * 16;
  float a0[16], a1[16], a2[16];
#pragma unroll
  for (int r = 0; r < 16; ++r) {
    size_t ro = (size_t)(r0 + r) * HD;
    a0[r] = bf2f(DT[ro + t]);
    a1[r] = bf2f(DT[ro + t + 256]);
    a2[r] = bf2f(DT[ro + t + 512]);
  }
  float g0 = gamma[t], g1 = gamma[t + 256], g2 = gamma[t + 512];
  float be0 = beta[t], be1 = beta[t + 256], be2 = beta[t + 512];
  float ps[16];
  const int lane = t & 63, wv = t >> 6;
#pragma unroll
  for (int r = 0; r < 16; ++r) ps[r] = a0[r] + a1[r] + a2[r];
#pragma unroll
  for (int r = 0; r < 16; ++r)
#pragma unroll
    for (int m = 1; m < 64; m <<= 1) ps[r] += __shfl_xor(ps[r], m);
  if (lane == 0) {
#pragma unroll
    for (int r = 0; r < 16; ++r) rbuf[wv][r] = ps[r];
  }
  __syncthreads();
  if (t < 16) mu_s[t] = (rbuf[0][t] + rbuf[1][t] + rbuf[2][t] + rbuf[3][t]) * (1.f / HD);
  __syncthreads();
#pragma unroll
  for (int r = 0; r < 16; ++r) {
    float mu = mu_s[r];
    float d0 = a0[r] - mu, d1 = a1[r] - mu, d2 = a2[r] - mu;
    ps[r] = d0 * d0 + d1 * d1 + d2 * d2;
  }
#pragma unroll
  for (int r = 0; r < 16; ++r)
#pragma unroll
    for (int m = 1; m < 64; m <<= 1) ps[r] += __shfl_xor(ps[r], m);
  if (lane == 0) {
#pragma unroll
    for (int r = 0; r < 16; ++r) rbuf[wv][r] = ps[r];
  }
  __syncthreads();
  if (t < 16)
    rs_s[t] = 1.f / sqrtf((rbuf[0][t] + rbuf[1][t] + rbuf[2][t] + rbuf[3][t]) * (1.f / HD) + 1e-12f);
  __syncthreads();
#pragma unroll
  for (int r = 0; r < 16; ++r) {
    float mu = mu_s[r], rs = rs_s[r];
    size_t ro = (size_t)(r0 + r) * HD;
    DT[ro + t]       = f2bf((a0[r] - mu) * rs * g0 + be0);
    DT[ro + t + 256] = f2bf((a1[r] - mu) * rs * g1 + be1);
    DT[ro + t + 512] = f2bf((a2[r] - mu) * rs * g2 + be2);
  }
}

// -- decoder GEMM: 2-phase double-buffered 256x256, counted vmcnt (T3/T4) --
// out = T @ WvB^T + bvoc. 512 thr / 8 waves (2Mx4N), per-wave C = 128x64.
__global__ __launch_bounds__(512) void gemm_kernel(
    const unsigned short* __restrict__ Tm, const unsigned short* __restrict__ Wv,
    const float* __restrict__ bvoc, float* __restrict__ out) {
  __shared__ unsigned short As[2][256 * 64];   // 64 KiB
  __shared__ unsigned short Bs[2][256 * 64];   // 64 KiB -> 128 KiB total
  const int t = threadIdx.x;
  const int lane = t & 63, wid = t >> 6;       // 8 waves
  const int wm = wid >> 2, wn = wid & 3;       // 2 x 4
  // XCD-aware bijective swizzle: nwg = 83*16 = 1328 = 8*166
  const int nbx = VOCP / 256;                  // 83
  int lid = blockIdx.y * nbx + blockIdx.x;
  int swz = (lid & 7) * 166 + (lid >> 3);
  const int m0 = (swz / nbx) * 256, n0 = (swz % nbx) * 256;
  const int lrow = lane & 15, lgrp = lane >> 4;
  f32x4 acc[8][4] = {};

  // stage one K-tile (A 256x64 + B 256x64) into buffer d: 8 gl_lds/thread.
  // LDS dest = wave-uniform base (lane scatter is implicit +lane*16);
  // source granule pre-swizzled by the proven row&7 XOR (rule 21).
  auto stage = [&](int d, int kt) {
#pragma unroll
    for (int q = 0; q < 4; ++q) {
      int s = q * 512 + wid * 64 + lane;       // this lane's 16B slot 0..2047
      int row = s >> 3, g = s & 7;
      int sg = g ^ (row & 7);
      unsigned short* da = &As[d][(q * 512 + wid * 64) * 8];
      unsigned short* db = &Bs[d][(q * 512 + wid * 64) * 8];
      gl_lds16(Tm + (size_t)(m0 + row) * HD + kt + sg * 8, da);
      gl_lds16(Wv + (size_t)(n0 + row) * HD + kt + sg * 8, db);
    }
  };

  stage(0, 0);                                  // prologue: tile 0 in flight
  for (int it = 0; it < 12; ++it) {
    int cur = it & 1;
    if (it < 11) {
      stage(cur ^ 1, (it + 1) * 64);            // prefetch next tile
      asm volatile("s_waitcnt vmcnt(8)" ::: "memory");  // cur tile landed
    } else {
      asm volatile("s_waitcnt vmcnt(0)" ::: "memory");
    }
    __builtin_amdgcn_s_barrier();               // all waves: cur tile ready
#pragma unroll
    for (int kk = 0; kk < 2; ++kk) {
      short8 bfr[4];
#pragma unroll
      for (int j = 0; j < 4; ++j) {
        int row = wn * 64 + j * 16 + lrow;
        int gg = (kk * 4 + lgrp) ^ (row & 7);   // swizzled read
        bfr[j] = *reinterpret_cast<const short8*>(&Bs[cur][row * 64 + gg * 8]);
      }
#pragma unroll
      for (int i = 0; i < 8; ++i) {
        int row = wm * 128 + i * 16 + lrow;
        int gg = (kk * 4 + lgrp) ^ (row & 7);
        short8 af = *reinterpret_cast<const short8*>(&As[cur][row * 64 + gg * 8]);
#pragma unroll
        for (int j = 0; j < 4; ++j)
          acc[i][j] = __builtin_amdgcn_mfma_f32_16x16x32_bf16(af, bfr[j], acc[i][j], 0, 0, 0);
      }
    }
    asm volatile("" ::: "memory");              // pin reads above the barrier
    __builtin_amdgcn_s_barrier();               // reads done -> buffer reusable
  }
#pragma unroll
  for (int j = 0; j < 4; ++j) {
    int col = n0 + wn * 64 + j * 16 + lrow;
    bool cok = col < VOC;
    float bv = cok ? bvoc[col] : 0.f;
#pragma unroll
    for (int i = 0; i < 8; ++i) {
      int rbase = m0 + wm * 128 + i * 16 + lgrp * 4;
#pragma unroll
      for (int e = 0; e < 4; ++e) {
        int row = rbase + e;
        if (cok && row < MROWS) out[(size_t)row * VOC + col] = acc[i][j][e] + bv;
      }
    }
  }
}

extern "C" void kernel_launch(void* const* d_in, const int* in_sizes, int n_in,
                              void* d_out, int out_size, void* d_ws, size_t ws_size,
                              hipStream_t stream) {
  (void)in_sizes; (void)n_in; (void)out_size; (void)ws_size;
  const float* cls  = (const float*)d_in[0];
  const float* Wih  = (const float*)d_in[1];
  const float* Whh  = (const float*)d_in[2];
  const float* bih  = (const float*)d_in[3];
  const float* bhh  = (const float*)d_in[4];
  const float* Wd   = (const float*)d_in[5];
  const float* bd   = (const float*)d_in[6];
  const float* gmm  = (const float*)d_in[7];
  const float* bet  = (const float*)d_in[8];
  const float* Wv   = (const float*)d_in[9];
  const float* bvoc = (const float*)d_in[10];
  char* ws = (char*)d_ws;
  uint32_t* hw = (uint32_t*)(ws + OFF_HW);
  unsigned short* HallB = (unsigned short*)(ws + OFF_HALLB);
  unsigned short* DT    = (unsigned short*)(ws + OFF_DT);
  unsigned short* WdB   = (unsigned short*)(ws + OFF_WDB);
  unsigned short* WvB   = (unsigned short*)(ws + OFF_WV);
  float* out = (float*)d_out;

  hipLaunchKernelGGL(zero_hw_kernel, dim3(48), dim3(256), 0, stream, hw);
  hipLaunchKernelGGL(lstm_kernel, dim3(256), dim3(256), 0, stream,
                     cls, Wih, Whh, bih, bhh, hw, HallB, Wd, WdB, Wv, WvB);
  hipLaunchKernelGGL(head_mm_kernel, dim3(HD / 128, MPAD / 128), dim3(256), 0, stream,
                     HallB, WdB, bd, DT);
  hipLaunchKernelGGL(ln_kernel, dim3(MPAD / 16), dim3(256), 0, stream,
                     DT, gmm, bet);
  hipLaunchKernelGGL(gemm_kernel, dim3(VOCP / 256, MPAD / 256), dim3(512), 0, stream,
                     DT, WvB, bvoc, out);
}